// Round 2
// baseline (404.178 us; speedup 1.0000x reference)
//
#include <hip/hip_runtime.h>
#include <cstdint>
#include <cstddef>

typedef _Float16 f16;
typedef _Float16 f16x4 __attribute__((ext_vector_type(4)));
typedef _Float16 f16x8 __attribute__((ext_vector_type(8)));
typedef float f32x4 __attribute__((ext_vector_type(4)));

#define DIM 1024
#define B_ 4
#define N_ 4096
#define TKP 288           // padded key count (256 tokens + null + pad to 9*32)
#define SCALE_ 8.0f
#define LOG2E 1.4426950408889634f

// ---- async global->LDS, 16B per lane (CK-style addrspace casts) ----
__device__ __forceinline__ void gload_lds16(const void* g, void* l) {
  __builtin_amdgcn_global_load_lds(
      reinterpret_cast<const __attribute__((address_space(1))) uint32_t*>(
          reinterpret_cast<uintptr_t>(g)),
      reinterpret_cast<__attribute__((address_space(3))) uint32_t*>(
          reinterpret_cast<uintptr_t>(l)),
      16, 0, 0);
}

// ---- weight transpose: W fp32 [K][N] -> WT f16 [N][K] ----
__global__ void transpose_w_kernel(const float* __restrict__ W, f16* __restrict__ WT,
                                   int K, int N) {
  __shared__ float tile[32][33];
  int nt = N >> 5;
  int tk = blockIdx.x / nt, tn = blockIdx.x % nt;
  int tx = threadIdx.x & 31, ty = threadIdx.x >> 5;  // 256 thr: ty 0..7
#pragma unroll
  for (int p = 0; p < 32; p += 8)
    tile[ty + p][tx] = W[(size_t)(tk * 32 + ty + p) * N + tn * 32 + tx];
  __syncthreads();
#pragma unroll
  for (int p = 0; p < 32; p += 8)
    WT[(size_t)(tn * 32 + ty + p) * K + tk * 32 + tx] = (f16)tile[tx][ty + p];
}

// ---- LayerNorm over 1024, one row per block; OUT_T = f16 or float ----
template <typename OUT_T>
__global__ void ln_kernel(const float* __restrict__ in, const float* __restrict__ g,
                          const float* __restrict__ bb, OUT_T* __restrict__ out) {
  int row = blockIdx.x;
  int t = threadIdx.x;  // 256
  const float4* rp = (const float4*)(in + (size_t)row * DIM);
  float4 v = rp[t];
  float s = v.x + v.y + v.z + v.w;
  float ss = v.x * v.x + v.y * v.y + v.z * v.z + v.w * v.w;
#pragma unroll
  for (int m = 1; m < 64; m <<= 1) { s += __shfl_xor(s, m); ss += __shfl_xor(ss, m); }
  __shared__ float red[8];
  int w = t >> 6;
  if ((t & 63) == 0) { red[w * 2] = s; red[w * 2 + 1] = ss; }
  __syncthreads();
  s = red[0] + red[2] + red[4] + red[6];
  ss = red[1] + red[3] + red[5] + red[7];
  float mean = s * (1.0f / DIM);
  float var = ss * (1.0f / DIM) - mean * mean;
  float rstd = rsqrtf(var + 1e-5f);
  float4 gv = ((const float4*)g)[t];
  float4 bv = ((const float4*)bb)[t];
  float o0 = (v.x - mean) * rstd * gv.x + bv.x;
  float o1 = (v.y - mean) * rstd * gv.y + bv.y;
  float o2 = (v.z - mean) * rstd * gv.z + bv.z;
  float o3 = (v.w - mean) * rstd * gv.w + bv.w;
  if constexpr (sizeof(OUT_T) == 2) {
    f16x4 h = {(f16)o0, (f16)o1, (f16)o2, (f16)o3};
    *(f16x4*)((f16*)out + (size_t)row * DIM + t * 4) = h;
  } else {
    float4 o = {o0, o1, o2, o3};
    *(float4*)((float*)out + (size_t)row * DIM + t * 4) = o;
  }
}

// ---- NT GEMM: A f16 [M][K], Bt f16 [N][K], C = A*Bt^T. 128x128 tile, BK=64 ----
// XCD-aware block swizzle (gridDim.x always % 8 == 0 at our shapes).
template <bool OUT_F32>
__global__ __launch_bounds__(256, 2) void gemm_nt_kernel(
    const f16* __restrict__ A, const f16* __restrict__ Bt, void* __restrict__ C,
    int M, int N, int K) {
  __shared__ f16 As[128 * 64];
  __shared__ f16 Bs[128 * 64];
  int nb = N >> 7;
  int cpx = gridDim.x >> 3;
  int wg = ((int)blockIdx.x & 7) * cpx + ((int)blockIdx.x >> 3);
  int bm = wg / nb, bn = wg % nb;
  int t = threadIdx.x;
  int lane = t & 63, w = t >> 6;
  int wm = w >> 1, wn = w & 1;       // 2x2 wave grid, each wave 64x64 output
  int r16 = lane & 15, g4 = lane >> 4;
  f32x4 acc[4][4] = {};
  for (int k0 = 0; k0 < K; k0 += 64) {
    // stage A,B tiles: [128 rows][64 k] f16, 16B chunks. LDS dest is LINEAR
    // (global_load_lds constraint); the global SOURCE is pre-swizzled
    // (chunk c -> c ^ (row&7)) so the ds_read side can XOR-swizzle (rule #21).
#pragma unroll
    for (int i = 0; i < 4; ++i) {
      int li = i * 256 + t;          // 0..1023 16B chunks
      int r = li >> 3, c = li & 7;
      int kc = ((c ^ (r & 7)) << 3); // element offset of swizzled chunk
      gload_lds16(A + (size_t)(bm * 128 + r) * K + k0 + kc, (char*)As + li * 16);
      gload_lds16(Bt + (size_t)(bn * 128 + r) * K + k0 + kc, (char*)Bs + li * 16);
    }
    asm volatile("s_waitcnt vmcnt(0)" ::: "memory");
    __syncthreads();
#pragma unroll
    for (int ks = 0; ks < 2; ++ks) {
      f16x8 af[4], bf[4];
#pragma unroll
      for (int mi = 0; mi < 4; ++mi) {
        int r = wm * 64 + mi * 16 + r16;
        int cidx = ks * 4 + g4;
        af[mi] = *(const f16x8*)(As + r * 64 + ((cidx ^ (r & 7)) << 3));
      }
#pragma unroll
      for (int ni = 0; ni < 4; ++ni) {
        int r = wn * 64 + ni * 16 + r16;
        int cidx = ks * 4 + g4;
        bf[ni] = *(const f16x8*)(Bs + r * 64 + ((cidx ^ (r & 7)) << 3));
      }
#pragma unroll
      for (int mi = 0; mi < 4; ++mi)
#pragma unroll
        for (int ni = 0; ni < 4; ++ni)
          acc[mi][ni] = __builtin_amdgcn_mfma_f32_16x16x32_f16(af[mi], bf[ni],
                                                               acc[mi][ni], 0, 0, 0);
    }
    __syncthreads();
  }
  // epilogue: C/D layout col = lane&15, row = (lane>>4)*4 + reg
  int cr0 = bm * 128 + wm * 64;
  int cc = bn * 128 + wn * 64 + r16;
#pragma unroll
  for (int mi = 0; mi < 4; ++mi)
#pragma unroll
    for (int ni = 0; ni < 4; ++ni)
#pragma unroll
      for (int j = 0; j < 4; ++j) {
        int row = cr0 + mi * 16 + g4 * 4 + j;
        int col = cc + ni * 16;
        if constexpr (OUT_F32)
          ((float*)C)[(size_t)row * N + col] = acc[mi][ni][j];
        else
          ((f16*)C)[(size_t)row * N + col] = (f16)acc[mi][ni][j];
      }
}

// ---- build K [bh][288][64] (l2-norm * k_scale, null@256, zeros 257..287)
//      and V^T [bh][64][288] (raw v, null@256, zeros 257..287) ----
__global__ void prep_kv_kernel(const f16* __restrict__ kv, const float* __restrict__ nullkv,
                               const float* __restrict__ ks, f16* __restrict__ Karr,
                               f16* __restrict__ Varr) {
  int bh = blockIdx.x;           // 64 blocks
  int b = bh >> 4, h = bh & 15;
  int t = threadIdx.x;           // 256
  __shared__ f16 vt[256][65];
  const f16* krow = kv + (size_t)(b * 256 + t) * 2048 + h * 64;
  const f16* vrow = krow + 1024;
  f16x8 kd[8];
  float ss = 0.0f;
#pragma unroll
  for (int i = 0; i < 8; ++i) {
    kd[i] = *(const f16x8*)(krow + i * 8);
#pragma unroll
    for (int j = 0; j < 8; ++j) { float x = (float)kd[i][j]; ss += x * x; }
  }
  float inv = 1.0f / fmaxf(sqrtf(ss), 1e-12f);
  f16* kout = Karr + ((size_t)bh * TKP + t) * 64;
#pragma unroll
  for (int i = 0; i < 8; ++i) {
    f16x8 o;
#pragma unroll
    for (int j = 0; j < 8; ++j) o[j] = (f16)((float)kd[i][j] * inv * ks[i * 8 + j]);
    *(f16x8*)(kout + i * 8) = o;
  }
#pragma unroll
  for (int i = 0; i < 8; ++i) {
    f16x8 vv = *(const f16x8*)(vrow + i * 8);
#pragma unroll
    for (int j = 0; j < 8; ++j) vt[t][i * 8 + j] = vv[j];
  }
  if (t < 32) {   // K rows 256..287
    f16* kr = Karr + ((size_t)bh * TKP + 256 + t) * 64;
    if (t == 0) {
      float ssn = 0.0f;
      for (int d = 0; d < 64; ++d) ssn += nullkv[d] * nullkv[d];
      float invn = 1.0f / fmaxf(sqrtf(ssn), 1e-12f);
      for (int d = 0; d < 64; ++d) kr[d] = (f16)(nullkv[d] * invn * ks[d]);
    } else {
      for (int d = 0; d < 64; ++d) kr[d] = (f16)0.0f;
    }
  }
  __syncthreads();
  f16* vbase = Varr + (size_t)bh * 64 * TKP;
  for (int d = 0; d < 64; ++d) vbase[(size_t)d * TKP + t] = vt[t][d];
#pragma unroll
  for (int i = 0; i < 8; ++i) {      // V keys 256..287 for all d
    int idx = i * 256 + t;
    int d = idx >> 5, key = 256 + (idx & 31);
    vbase[(size_t)d * TKP + key] = (key == 256) ? (f16)nullkv[64 + d] : (f16)0.0f;
  }
}

// ---- flash attention: 4 waves/block, 64 q-rows/wave, 32-key tiles ----
// q l2-norm * q_scale fused into the Q-fragment load (row sum-of-squares
// completes across lanes differing in bits 4..5 -> shfl_xor 16/32).
__global__ __launch_bounds__(256, 2) void attn_kernel(
    const f16* __restrict__ Q, const f16* __restrict__ Karr,
    const f16* __restrict__ Varr, const float* __restrict__ qs,
    f16* __restrict__ O) {
  int qb = blockIdx.x & 15, bh = blockIdx.x >> 4;
  int b = bh >> 4, h = bh & 15;
  int t = threadIdx.x, lane = t & 63, w = t >> 6;
  int r16 = lane & 15, g4 = lane >> 4;
  int row0 = b * N_ + qb * 256 + w * 64;
  int col0 = h * 64;
  const f16* Kp = Karr + (size_t)bh * TKP * 64;
  const f16* Vp = Varr + (size_t)bh * 64 * TKP;
  __shared__ f16 Plds[4][64 * 40];   // per-wave P buffer [64 rows][40 (32 used)]
  f16* Pw = &Plds[w][0];
  float qsv[2][8];
#pragma unroll
  for (int kdh = 0; kdh < 2; ++kdh)
#pragma unroll
    for (int i = 0; i < 8; ++i) qsv[kdh][i] = qs[kdh * 32 + g4 * 8 + i];
  f16x8 qf[4][2];
#pragma unroll
  for (int mi = 0; mi < 4; ++mi) {
    float f[2][8];
    float ssq = 0.0f;
#pragma unroll
    for (int kdh = 0; kdh < 2; ++kdh) {
      f16x8 v = *(const f16x8*)(Q + (size_t)(row0 + mi * 16 + r16) * DIM +
                                col0 + kdh * 32 + g4 * 8);
#pragma unroll
      for (int i = 0; i < 8; ++i) { f[kdh][i] = (float)v[i]; ssq += f[kdh][i] * f[kdh][i]; }
    }
    ssq += __shfl_xor(ssq, 16);
    ssq += __shfl_xor(ssq, 32);
    float inv = 1.0f / fmaxf(sqrtf(ssq), 1e-12f);
#pragma unroll
    for (int kdh = 0; kdh < 2; ++kdh) {
      f16x8 o;
#pragma unroll
      for (int i = 0; i < 8; ++i) o[i] = (f16)(f[kdh][i] * inv * qsv[kdh][i]);
      qf[mi][kdh] = o;
    }
  }
  f32x4 o[4][4] = {};
  float mrow[4][4], lrow[4][4];
#pragma unroll
  for (int mi = 0; mi < 4; ++mi)
#pragma unroll
    for (int j = 0; j < 4; ++j) { mrow[mi][j] = -1e30f; lrow[mi][j] = 0.0f; }
  for (int kt = 0; kt < 9; ++kt) {
    int key0 = kt * 32;
    f16x8 kf[2][2];
#pragma unroll
    for (int ni = 0; ni < 2; ++ni)
#pragma unroll
      for (int kdh = 0; kdh < 2; ++kdh)
        kf[ni][kdh] = *(const f16x8*)(Kp + (size_t)(key0 + ni * 16 + r16) * 64 +
                                      kdh * 32 + g4 * 8);
    f32x4 s[4][2] = {};
#pragma unroll
    for (int kdh = 0; kdh < 2; ++kdh)
#pragma unroll
      for (int mi = 0; mi < 4; ++mi)
#pragma unroll
        for (int ni = 0; ni < 2; ++ni)
          s[mi][ni] = __builtin_amdgcn_mfma_f32_16x16x32_f16(qf[mi][kdh], kf[ni][kdh],
                                                             s[mi][ni], 0, 0, 0);
    bool va = (key0 + r16 <= 256), vb = (key0 + 16 + r16 <= 256);
#pragma unroll
    for (int mi = 0; mi < 4; ++mi) {
#pragma unroll
      for (int j = 0; j < 4; ++j) {
        float s0 = va ? s[mi][0][j] * SCALE_ : -1e30f;
        float s1 = vb ? s[mi][1][j] * SCALE_ : -1e30f;
        float tm = fmaxf(s0, s1);
        tm = fmaxf(tm, __shfl_xor(tm, 1));
        tm = fmaxf(tm, __shfl_xor(tm, 2));
        tm = fmaxf(tm, __shfl_xor(tm, 4));
        tm = fmaxf(tm, __shfl_xor(tm, 8));
        float nm = fmaxf(mrow[mi][j], tm);
        float corr = exp2f((mrow[mi][j] - nm) * LOG2E);
        mrow[mi][j] = nm;
        float p0 = exp2f((s0 - nm) * LOG2E);
        float p1 = exp2f((s1 - nm) * LOG2E);
        int prow = mi * 16 + g4 * 4 + j;
        Pw[prow * 40 + r16] = (f16)p0;
        Pw[prow * 40 + 16 + r16] = (f16)p1;
        float rs = p0 + p1;
        rs += __shfl_xor(rs, 1); rs += __shfl_xor(rs, 2);
        rs += __shfl_xor(rs, 4); rs += __shfl_xor(rs, 8);
        lrow[mi][j] = lrow[mi][j] * corr + rs;
#pragma unroll
        for (int nd = 0; nd < 4; ++nd) o[mi][nd][j] *= corr;
      }
    }
    f16x8 vf[4];
#pragma unroll
    for (int nd = 0; nd < 4; ++nd)
      vf[nd] = *(const f16x8*)(Vp + (size_t)(nd * 16 + r16) * TKP + key0 + g4 * 8);
#pragma unroll
    for (int mi = 0; mi < 4; ++mi) {
      f16x8 pa = *(const f16x8*)(Pw + (mi * 16 + r16) * 40 + g4 * 8);
#pragma unroll
      for (int nd = 0; nd < 4; ++nd)
        o[mi][nd] = __builtin_amdgcn_mfma_f32_16x16x32_f16(pa, vf[nd], o[mi][nd], 0, 0, 0);
    }
  }
#pragma unroll
  for (int mi = 0; mi < 4; ++mi)
#pragma unroll
    for (int j = 0; j < 4; ++j) {
      float inv = 1.0f / lrow[mi][j];
      int row = row0 + mi * 16 + g4 * 4 + j;
#pragma unroll
      for (int nd = 0; nd < 4; ++nd)
        O[(size_t)row * DIM + col0 + nd * 16 + r16] = (f16)(o[mi][nd][j] * inv);
    }
}

extern "C" void kernel_launch(void* const* d_in, const int* in_sizes, int n_in,
                              void* d_out, int out_size, void* d_ws, size_t ws_size,
                              hipStream_t stream) {
  const float* x      = (const float*)d_in[0];
  const float* ctx    = (const float*)d_in[1];
  const float* Wq     = (const float*)d_in[2];
  const float* Wkv    = (const float*)d_in[3];
  const float* Wo     = (const float*)d_in[4];
  const float* nullkv = (const float*)d_in[5];
  const float* qs     = (const float*)d_in[6];
  const float* ks     = (const float*)d_in[7];
  const float* g_in   = (const float*)d_in[8];
  const float* b_in   = (const float*)d_in[9];
  const float* g_ctx  = (const float*)d_in[10];
  const float* b_ctx  = (const float*)d_in[11];
  const float* g_out  = (const float*)d_in[12];
  const float* b_out  = (const float*)d_in[13];

  // Compact workspace plan (peak 116 MB), lifetimes:
  //   wqT 0-2, wkvT 2-6, woT 6-8            (live: whole run)
  //   karr 8-11, varr 11-14                 (prep_kv -> attn)
  //   cn 14-16   (ln ctx -> gemm kv)        kvb 16-20 (gemm kv -> prep_kv)
  //   xn 20-52   (ln x -> gemm q)           q_raw 52-84 (gemm q -> attn)
  //   aout 20-52 (attn -> gemm o; overlays dead xn)
  //   out2 52-116 f32 (gemm o -> ln out; overlays dead q_raw)
  char* ws = (char*)d_ws;
  const size_t MB = 1ull << 20;
  f16* wqT   = (f16*)(ws + 0);
  f16* wkvT  = (f16*)(ws + 2 * MB);
  f16* woT   = (f16*)(ws + 6 * MB);
  f16* karr  = (f16*)(ws + 8 * MB);
  f16* varr  = (f16*)(ws + 11 * MB);
  f16* cn    = (f16*)(ws + 14 * MB);
  f16* kvb   = (f16*)(ws + 16 * MB);
  f16* xn    = (f16*)(ws + 20 * MB);
  f16* q_raw = (f16*)(ws + 52 * MB);
  f16* aout  = (f16*)(ws + 20 * MB);
  float* out2 = (float*)(ws + 52 * MB);

  transpose_w_kernel<<<1024, 256, 0, stream>>>(Wq, wqT, 1024, 1024);
  transpose_w_kernel<<<2048, 256, 0, stream>>>(Wkv, wkvT, 1024, 2048);
  transpose_w_kernel<<<1024, 256, 0, stream>>>(Wo, woT, 1024, 1024);

  ln_kernel<f16><<<16384, 256, 0, stream>>>(x, g_in, b_in, xn);
  ln_kernel<f16><<<1024, 256, 0, stream>>>(ctx, g_ctx, b_ctx, cn);

  gemm_nt_kernel<false><<<(16384 / 128) * (1024 / 128), 256, 0, stream>>>(
      xn, wqT, (void*)q_raw, 16384, 1024, 1024);
  gemm_nt_kernel<false><<<(1024 / 128) * (2048 / 128), 256, 0, stream>>>(
      cn, wkvT, (void*)kvb, 1024, 2048, 1024);

  prep_kv_kernel<<<64, 256, 0, stream>>>(kvb, nullkv, ks, karr, varr);

  attn_kernel<<<1024, 256, 0, stream>>>(q_raw, karr, varr, qs, aout);

  gemm_nt_kernel<true><<<(16384 / 128) * (1024 / 128), 256, 0, stream>>>(
      aout, woT, (void*)out2, 16384, 1024, 1024);

  ln_kernel<float><<<16384, 256, 0, stream>>>(out2, g_out, b_out, (float*)d_out);
}

// Round 4
// 356.715 us; speedup vs baseline: 1.1331x; 1.1331x over previous
//
#include <hip/hip_runtime.h>
#include <cstdint>
#include <cstddef>

typedef _Float16 f16;
typedef _Float16 f16x4 __attribute__((ext_vector_type(4)));
typedef _Float16 f16x8 __attribute__((ext_vector_type(8)));
typedef float f32x4 __attribute__((ext_vector_type(4)));

#define DIM 1024
#define B_ 4
#define N_ 4096
#define TKP 288           // padded key count (256 tokens + null + pad to 9*32)
#define SCALE_ 8.0f
#define LOG2E 1.4426950408889634f

// ---- async global->LDS, 16B per lane (CK-style addrspace casts) ----
__device__ __forceinline__ void gload_lds16(const void* g, void* l) {
  __builtin_amdgcn_global_load_lds(
      reinterpret_cast<const __attribute__((address_space(1))) uint32_t*>(
          reinterpret_cast<uintptr_t>(g)),
      reinterpret_cast<__attribute__((address_space(3))) uint32_t*>(
          reinterpret_cast<uintptr_t>(l)),
      16, 0, 0);
}

// ---- weight transpose: W fp32 [K][N] -> WT f16 [N][K] ----
__global__ void transpose_w_kernel(const float* __restrict__ W, f16* __restrict__ WT,
                                   int K, int N) {
  __shared__ float tile[32][33];
  int nt = N >> 5;
  int tk = blockIdx.x / nt, tn = blockIdx.x % nt;
  int tx = threadIdx.x & 31, ty = threadIdx.x >> 5;  // 256 thr: ty 0..7
#pragma unroll
  for (int p = 0; p < 32; p += 8)
    tile[ty + p][tx] = W[(size_t)(tk * 32 + ty + p) * N + tn * 32 + tx];
  __syncthreads();
#pragma unroll
  for (int p = 0; p < 32; p += 8)
    WT[(size_t)(tn * 32 + ty + p) * K + tk * 32 + tx] = (f16)tile[tx][ty + p];
}

// ---- LayerNorm over 1024, one row per block; OUT_T = f16 or float ----
template <typename OUT_T>
__global__ void ln_kernel(const float* __restrict__ in, const float* __restrict__ g,
                          const float* __restrict__ bb, OUT_T* __restrict__ out) {
  int row = blockIdx.x;
  int t = threadIdx.x;  // 256
  const float4* rp = (const float4*)(in + (size_t)row * DIM);
  float4 v = rp[t];
  float s = v.x + v.y + v.z + v.w;
  float ss = v.x * v.x + v.y * v.y + v.z * v.z + v.w * v.w;
#pragma unroll
  for (int m = 1; m < 64; m <<= 1) { s += __shfl_xor(s, m); ss += __shfl_xor(ss, m); }
  __shared__ float red[8];
  int w = t >> 6;
  if ((t & 63) == 0) { red[w * 2] = s; red[w * 2 + 1] = ss; }
  __syncthreads();
  s = red[0] + red[2] + red[4] + red[6];
  ss = red[1] + red[3] + red[5] + red[7];
  float mean = s * (1.0f / DIM);
  float var = ss * (1.0f / DIM) - mean * mean;
  float rstd = rsqrtf(var + 1e-5f);
  float4 gv = ((const float4*)g)[t];
  float4 bv = ((const float4*)bb)[t];
  float o0 = (v.x - mean) * rstd * gv.x + bv.x;
  float o1 = (v.y - mean) * rstd * gv.y + bv.y;
  float o2 = (v.z - mean) * rstd * gv.z + bv.z;
  float o3 = (v.w - mean) * rstd * gv.w + bv.w;
  if constexpr (sizeof(OUT_T) == 2) {
    f16x4 h = {(f16)o0, (f16)o1, (f16)o2, (f16)o3};
    *(f16x4*)((f16*)out + (size_t)row * DIM + t * 4) = h;
  } else {
    float4 o = {o0, o1, o2, o3};
    *(float4*)((float*)out + (size_t)row * DIM + t * 4) = o;
  }
}

// ---- NT GEMM: A f16 [M][K], Bt f16 [N][K], C = A*Bt^T. 128x128 tile, BK=64 ----
// XCD-aware block swizzle (gridDim.x always % 8 == 0 at our shapes).
template <bool OUT_F32>
__global__ __launch_bounds__(256, 2) void gemm_nt_kernel(
    const f16* __restrict__ A, const f16* __restrict__ Bt, void* __restrict__ C,
    int M, int N, int K) {
  __shared__ f16 As[128 * 64];
  __shared__ f16 Bs[128 * 64];
  int nb = N >> 7;
  int cpx = gridDim.x >> 3;
  int wg = ((int)blockIdx.x & 7) * cpx + ((int)blockIdx.x >> 3);
  int bm = wg / nb, bn = wg % nb;
  int t = threadIdx.x;
  int lane = t & 63, w = t >> 6;
  int wm = w >> 1, wn = w & 1;       // 2x2 wave grid, each wave 64x64 output
  int r16 = lane & 15, g4 = lane >> 4;
  f32x4 acc[4][4] = {};
  for (int k0 = 0; k0 < K; k0 += 64) {
    // stage A,B tiles: [128 rows][64 k] f16, 16B chunks. LDS dest is LINEAR
    // (global_load_lds constraint); the global SOURCE is pre-swizzled
    // (chunk c -> c ^ (row&7)) so the ds_read side can XOR-swizzle (rule #21).
#pragma unroll
    for (int i = 0; i < 4; ++i) {
      int li = i * 256 + t;          // 0..1023 16B chunks
      int r = li >> 3, c = li & 7;
      int kc = ((c ^ (r & 7)) << 3); // element offset of swizzled chunk
      gload_lds16(A + (size_t)(bm * 128 + r) * K + k0 + kc, (char*)As + li * 16);
      gload_lds16(Bt + (size_t)(bn * 128 + r) * K + k0 + kc, (char*)Bs + li * 16);
    }
    asm volatile("s_waitcnt vmcnt(0)" ::: "memory");
    __syncthreads();
#pragma unroll
    for (int ks = 0; ks < 2; ++ks) {
      f16x8 af[4], bf[4];
#pragma unroll
      for (int mi = 0; mi < 4; ++mi) {
        int r = wm * 64 + mi * 16 + r16;
        int cidx = ks * 4 + g4;
        af[mi] = *(const f16x8*)(As + r * 64 + ((cidx ^ (r & 7)) << 3));
      }
#pragma unroll
      for (int ni = 0; ni < 4; ++ni) {
        int r = wn * 64 + ni * 16 + r16;
        int cidx = ks * 4 + g4;
        bf[ni] = *(const f16x8*)(Bs + r * 64 + ((cidx ^ (r & 7)) << 3));
      }
#pragma unroll
      for (int mi = 0; mi < 4; ++mi)
#pragma unroll
        for (int ni = 0; ni < 4; ++ni)
          acc[mi][ni] = __builtin_amdgcn_mfma_f32_16x16x32_f16(af[mi], bf[ni],
                                                               acc[mi][ni], 0, 0, 0);
    }
    __syncthreads();
  }
  // epilogue: C/D layout col = lane&15, row = (lane>>4)*4 + reg
  int cr0 = bm * 128 + wm * 64;
  int cc = bn * 128 + wn * 64 + r16;
#pragma unroll
  for (int mi = 0; mi < 4; ++mi)
#pragma unroll
    for (int ni = 0; ni < 4; ++ni)
#pragma unroll
      for (int j = 0; j < 4; ++j) {
        int row = cr0 + mi * 16 + g4 * 4 + j;
        int col = cc + ni * 16;
        if constexpr (OUT_F32)
          ((float*)C)[(size_t)row * N + col] = acc[mi][ni][j];
        else
          ((f16*)C)[(size_t)row * N + col] = (f16)acc[mi][ni][j];
      }
}

// ---- build K [bh][288][64] (l2-norm * k_scale, null@256, zeros 257..287)
//      and V^T [bh][64][288] with keys PERMUTED within each 32-group:
//      key kk -> col 2*(kk&15) + (kk>>4), matching the packed-P k-slot order.
__global__ void prep_kv_kernel(const f16* __restrict__ kv, const float* __restrict__ nullkv,
                               const float* __restrict__ ks, f16* __restrict__ Karr,
                               f16* __restrict__ Varr) {
  int bh = blockIdx.x;           // 64 blocks
  int b = bh >> 4, h = bh & 15;
  int t = threadIdx.x;           // 256
  __shared__ f16 vt[256][65];
  const f16* krow = kv + (size_t)(b * 256 + t) * 2048 + h * 64;
  const f16* vrow = krow + 1024;
  f16x8 kd[8];
  float ss = 0.0f;
#pragma unroll
  for (int i = 0; i < 8; ++i) {
    kd[i] = *(const f16x8*)(krow + i * 8);
#pragma unroll
    for (int j = 0; j < 8; ++j) { float x = (float)kd[i][j]; ss += x * x; }
  }
  float inv = 1.0f / fmaxf(sqrtf(ss), 1e-12f);
  f16* kout = Karr + ((size_t)bh * TKP + t) * 64;
#pragma unroll
  for (int i = 0; i < 8; ++i) {
    f16x8 o;
#pragma unroll
    for (int j = 0; j < 8; ++j) o[j] = (f16)((float)kd[i][j] * inv * ks[i * 8 + j]);
    *(f16x8*)(kout + i * 8) = o;
  }
#pragma unroll
  for (int i = 0; i < 8; ++i) {
    f16x8 vv = *(const f16x8*)(vrow + i * 8);
#pragma unroll
    for (int j = 0; j < 8; ++j) vt[t][i * 8 + j] = vv[j];
  }
  if (t < 32) {   // K rows 256..287
    f16* kr = Karr + ((size_t)bh * TKP + 256 + t) * 64;
    if (t == 0) {
      float ssn = 0.0f;
      for (int d = 0; d < 64; ++d) ssn += nullkv[d] * nullkv[d];
      float invn = 1.0f / fmaxf(sqrtf(ssn), 1e-12f);
      for (int d = 0; d < 64; ++d) kr[d] = (f16)(nullkv[d] * invn * ks[d]);
    } else {
      for (int d = 0; d < 64; ++d) kr[d] = (f16)0.0f;
    }
  }
  __syncthreads();
  f16* vbase = Varr + (size_t)bh * 64 * TKP;
  int pcol = (t & ~31) | (((t & 15) << 1) | ((t >> 4) & 1));  // permuted key col
  for (int d = 0; d < 64; ++d) vbase[(size_t)d * TKP + pcol] = vt[t][d];
#pragma unroll
  for (int i = 0; i < 8; ++i) {      // V keys 256..287 (perm maps 256->256; rest zero)
    int idx = i * 256 + t;
    int d = idx >> 5, key = 256 + (idx & 31);
    vbase[(size_t)d * TKP + key] = (key == 256) ? (f16)nullkv[64 + d] : (f16)0.0f;
  }
}

// ---- flash attention, fixed-bound softmax (scores bounded by Cauchy-Schwarz:
//      |s| <= SCALE*max|qs|*max|ks|), no online max, deferred row-sum.
//      4 waves/block, 32 q-rows/wave, 32-key tiles, 2048 blocks.
__global__ __launch_bounds__(256, 4) void attn_kernel(
    const f16* __restrict__ Q, const f16* __restrict__ Karr,
    const f16* __restrict__ Varr, const float* __restrict__ qs,
    const float* __restrict__ ksc, f16* __restrict__ O) {
  // chunked XCD swizzle: 2048 blocks -> 256 contiguous per XCD (8 heads' K/V per L2)
  int wgid = ((int)blockIdx.x & 7) * 256 + ((int)blockIdx.x >> 3);
  int qb = wgid & 31, bh = wgid >> 5;
  int b = bh >> 4, h = bh & 15;
  int t = threadIdx.x, lane = t & 63, w = t >> 6;
  int r16 = lane & 15, g4 = lane >> 4;
  int row0 = b * N_ + qb * 128 + w * 32;
  int col0 = h * 64;
  const f16* Kp = Karr + (size_t)bh * TKP * 64;
  const f16* Vp = Varr + (size_t)bh * 64 * TKP;
  __shared__ f16 Plds[4][32 * 40];   // per-wave P buffer [32 rows][40 (32 used)]
  f16* Pw = &Plds[w][0];
  // score bound M = SCALE * max|qs| * max|ks|  (==8 for unit scales)
  float mq = fabsf(qs[lane]), mk = fabsf(ksc[lane]);
#pragma unroll
  for (int m = 1; m < 64; m <<= 1) {
    mq = fmaxf(mq, __shfl_xor(mq, m));
    mk = fmaxf(mk, __shfl_xor(mk, m));
  }
  const float c1 = SCALE_ * LOG2E;
  const float c2 = SCALE_ * mq * mk * LOG2E;
  // Q fragments with fused l2-norm * q_scale
  float qsv[2][8];
#pragma unroll
  for (int kdh = 0; kdh < 2; ++kdh)
#pragma unroll
    for (int i = 0; i < 8; ++i) qsv[kdh][i] = qs[kdh * 32 + g4 * 8 + i];
  f16x8 qf[2][2];
#pragma unroll
  for (int mi = 0; mi < 2; ++mi) {
    float f[2][8];
    float ssq = 0.0f;
#pragma unroll
    for (int kdh = 0; kdh < 2; ++kdh) {
      f16x8 v = *(const f16x8*)(Q + (size_t)(row0 + mi * 16 + r16) * DIM +
                                col0 + kdh * 32 + g4 * 8);
#pragma unroll
      for (int i = 0; i < 8; ++i) { f[kdh][i] = (float)v[i]; ssq += f[kdh][i] * f[kdh][i]; }
    }
    ssq += __shfl_xor(ssq, 16);
    ssq += __shfl_xor(ssq, 32);
    float inv = 1.0f / fmaxf(sqrtf(ssq), 1e-12f);
#pragma unroll
    for (int kdh = 0; kdh < 2; ++kdh) {
      f16x8 o;
#pragma unroll
      for (int i = 0; i < 8; ++i) o[i] = (f16)(f[kdh][i] * inv * qsv[kdh][i]);
      qf[mi][kdh] = o;
    }
  }
  f32x4 o[2][4] = {};
  float part[2][4] = {};   // per-lane partial softmax denominators
  for (int kt = 0; kt < 9; ++kt) {
    int key0 = kt * 32;
    f16x8 kf[2][2];
#pragma unroll
    for (int ni = 0; ni < 2; ++ni)
#pragma unroll
      for (int kdh = 0; kdh < 2; ++kdh)
        kf[ni][kdh] = *(const f16x8*)(Kp + (size_t)(key0 + ni * 16 + r16) * 64 +
                                      kdh * 32 + g4 * 8);
    f32x4 s[2][2] = {};
    __builtin_amdgcn_s_setprio(1);
#pragma unroll
    for (int kdh = 0; kdh < 2; ++kdh)
#pragma unroll
      for (int mi = 0; mi < 2; ++mi)
#pragma unroll
        for (int ni = 0; ni < 2; ++ni)
          s[mi][ni] = __builtin_amdgcn_mfma_f32_16x16x32_f16(qf[mi][kdh], kf[ni][kdh],
                                                             s[mi][ni], 0, 0, 0);
    __builtin_amdgcn_s_setprio(0);
    bool va = (key0 + r16 <= 256), vb = (key0 + 16 + r16 <= 256);
#pragma unroll
    for (int mi = 0; mi < 2; ++mi) {
#pragma unroll
      for (int j = 0; j < 4; ++j) {
        float p0 = exp2f(s[mi][0][j] * c1 - c2);
        float p1 = exp2f(s[mi][1][j] * c1 - c2);
        p0 = va ? p0 : 0.0f;
        p1 = vb ? p1 : 0.0f;
        part[mi][j] += p0 + p1;
        int prow = mi * 16 + g4 * 4 + j;
        // pack {p0,p1} -> one b32 write; k-slot order (2*r16, 2*r16+1) matches
        // the permuted V^T columns written by prep_kv.
        auto pk = __builtin_amdgcn_cvt_pkrtz(p0, p1);  // __fp16 ext_vector(2)
        ((uint32_t*)(Pw + prow * 40))[r16] = __builtin_bit_cast(uint32_t, pk);
      }
    }
    f16x8 vf[4];
#pragma unroll
    for (int nd = 0; nd < 4; ++nd)
      vf[nd] = *(const f16x8*)(Vp + (size_t)(nd * 16 + r16) * TKP + key0 + g4 * 8);
    __builtin_amdgcn_s_setprio(1);
#pragma unroll
    for (int mi = 0; mi < 2; ++mi) {
      f16x8 pa = *(const f16x8*)(Pw + (mi * 16 + r16) * 40 + g4 * 8);
#pragma unroll
      for (int nd = 0; nd < 4; ++nd)
        o[mi][nd] = __builtin_amdgcn_mfma_f32_16x16x32_f16(pa, vf[nd], o[mi][nd], 0, 0, 0);
    }
    __builtin_amdgcn_s_setprio(0);
  }
  // one deferred row-sum reduction (across the 16 r16 lanes)
#pragma unroll
  for (int mi = 0; mi < 2; ++mi)
#pragma unroll
    for (int j = 0; j < 4; ++j) {
      float v = part[mi][j];
      v += __shfl_xor(v, 1); v += __shfl_xor(v, 2);
      v += __shfl_xor(v, 4); v += __shfl_xor(v, 8);
      part[mi][j] = v;
    }
#pragma unroll
  for (int mi = 0; mi < 2; ++mi)
#pragma unroll
    for (int j = 0; j < 4; ++j) {
      float inv = 1.0f / part[mi][j];
      int row = row0 + mi * 16 + g4 * 4 + j;
#pragma unroll
      for (int nd = 0; nd < 4; ++nd)
        O[(size_t)row * DIM + col0 + nd * 16 + r16] = (f16)(o[mi][nd][j] * inv);
    }
}

extern "C" void kernel_launch(void* const* d_in, const int* in_sizes, int n_in,
                              void* d_out, int out_size, void* d_ws, size_t ws_size,
                              hipStream_t stream) {
  const float* x      = (const float*)d_in[0];
  const float* ctx    = (const float*)d_in[1];
  const float* Wq     = (const float*)d_in[2];
  const float* Wkv    = (const float*)d_in[3];
  const float* Wo     = (const float*)d_in[4];
  const float* nullkv = (const float*)d_in[5];
  const float* qs     = (const float*)d_in[6];
  const float* ks     = (const float*)d_in[7];
  const float* g_in   = (const float*)d_in[8];
  const float* b_in   = (const float*)d_in[9];
  const float* g_ctx  = (const float*)d_in[10];
  const float* b_ctx  = (const float*)d_in[11];
  const float* g_out  = (const float*)d_in[12];
  const float* b_out  = (const float*)d_in[13];

  // Workspace plan (peak 116 MB):
  //   wqT 0-2, wkvT 2-6, woT 6-8            (live: whole run)
  //   karr 8-11, varr 11-14                 (prep_kv -> attn)
  //   cn 14-16, kvb 16-20
  //   xn 20-52 (ln x -> gemm q)             q_raw 52-84 (gemm q -> attn)
  //   aout 20-52 (attn -> gemm o; overlays dead xn)
  //   out2 52-116 f32 (gemm o -> ln out; overlays dead q_raw)
  char* ws = (char*)d_ws;
  const size_t MB = 1ull << 20;
  f16* wqT   = (f16*)(ws + 0);
  f16* wkvT  = (f16*)(ws + 2 * MB);
  f16* woT   = (f16*)(ws + 6 * MB);
  f16* karr  = (f16*)(ws + 8 * MB);
  f16* varr  = (f16*)(ws + 11 * MB);
  f16* cn    = (f16*)(ws + 14 * MB);
  f16* kvb   = (f16*)(ws + 16 * MB);
  f16* xn    = (f16*)(ws + 20 * MB);
  f16* q_raw = (f16*)(ws + 52 * MB);
  f16* aout  = (f16*)(ws + 20 * MB);
  float* out2 = (float*)(ws + 52 * MB);

  transpose_w_kernel<<<1024, 256, 0, stream>>>(Wq, wqT, 1024, 1024);
  transpose_w_kernel<<<2048, 256, 0, stream>>>(Wkv, wkvT, 1024, 2048);
  transpose_w_kernel<<<1024, 256, 0, stream>>>(Wo, woT, 1024, 1024);

  ln_kernel<f16><<<16384, 256, 0, stream>>>(x, g_in, b_in, xn);
  ln_kernel<f16><<<1024, 256, 0, stream>>>(ctx, g_ctx, b_ctx, cn);

  gemm_nt_kernel<false><<<(16384 / 128) * (1024 / 128), 256, 0, stream>>>(
      xn, wqT, (void*)q_raw, 16384, 1024, 1024);
  gemm_nt_kernel<false><<<(1024 / 128) * (2048 / 128), 256, 0, stream>>>(
      cn, wkvT, (void*)kvb, 1024, 2048, 1024);

  prep_kv_kernel<<<64, 256, 0, stream>>>(kvb, nullkv, ks, karr, varr);

  attn_kernel<<<2048, 256, 0, stream>>>(q_raw, karr, varr, qs, ks, aout);

  gemm_nt_kernel<true><<<(16384 / 128) * (1024 / 128), 256, 0, stream>>>(
      aout, woT, (void*)out2, 16384, 1024, 1024);

  ln_kernel<float><<<16384, 256, 0, stream>>>(out2, g_out, b_out, (float*)d_out);
}

// Round 5
// 339.534 us; speedup vs baseline: 1.1904x; 1.0506x over previous
//
#include <hip/hip_runtime.h>
#include <cstdint>
#include <cstddef>

typedef _Float16 f16;
typedef _Float16 f16x4 __attribute__((ext_vector_type(4)));
typedef _Float16 f16x8 __attribute__((ext_vector_type(8)));
typedef float f32x4 __attribute__((ext_vector_type(4)));
typedef __fp16 h16x2 __attribute__((ext_vector_type(2)));

#define DIM 1024
#define B_ 4
#define N_ 4096
#define TKP 288           // padded key count (256 tokens + null + pad to 9*32)
#define SCALE_ 8.0f
#define LOG2E 1.4426950408889634f

// ---- async global->LDS, 16B per lane (CK-style addrspace casts) ----
__device__ __forceinline__ void gload_lds16(const void* g, void* l) {
  __builtin_amdgcn_global_load_lds(
      reinterpret_cast<const __attribute__((address_space(1))) uint32_t*>(
          reinterpret_cast<uintptr_t>(g)),
      reinterpret_cast<__attribute__((address_space(3))) uint32_t*>(
          reinterpret_cast<uintptr_t>(l)),
      16, 0, 0);
}

// ---- weight transpose: W fp32 [K][N] -> WT f16 [N][K] ----
__global__ void transpose_w_kernel(const float* __restrict__ W, f16* __restrict__ WT,
                                   int K, int N) {
  __shared__ float tile[32][33];
  int nt = N >> 5;
  int tk = blockIdx.x / nt, tn = blockIdx.x % nt;
  int tx = threadIdx.x & 31, ty = threadIdx.x >> 5;  // 256 thr: ty 0..7
#pragma unroll
  for (int p = 0; p < 32; p += 8)
    tile[ty + p][tx] = W[(size_t)(tk * 32 + ty + p) * N + tn * 32 + tx];
  __syncthreads();
#pragma unroll
  for (int p = 0; p < 32; p += 8)
    WT[(size_t)(tn * 32 + ty + p) * K + tk * 32 + tx] = (f16)tile[tx][ty + p];
}

// ---- LayerNorm over 1024, one row per block; IN_T/OUT_T = f16 or float ----
template <typename IN_T, typename OUT_T>
__global__ void ln_kernel(const IN_T* __restrict__ in, const float* __restrict__ g,
                          const float* __restrict__ bb, OUT_T* __restrict__ out) {
  int row = blockIdx.x;
  int t = threadIdx.x;  // 256
  float4 v;
  if constexpr (sizeof(IN_T) == 2) {
    f16x4 h = ((const f16x4*)((const f16*)in + (size_t)row * DIM))[t];
    v = {(float)h[0], (float)h[1], (float)h[2], (float)h[3]};
  } else {
    v = ((const float4*)((const float*)in + (size_t)row * DIM))[t];
  }
  float s = v.x + v.y + v.z + v.w;
  float ss = v.x * v.x + v.y * v.y + v.z * v.z + v.w * v.w;
#pragma unroll
  for (int m = 1; m < 64; m <<= 1) { s += __shfl_xor(s, m); ss += __shfl_xor(ss, m); }
  __shared__ float red[8];
  int w = t >> 6;
  if ((t & 63) == 0) { red[w * 2] = s; red[w * 2 + 1] = ss; }
  __syncthreads();
  s = red[0] + red[2] + red[4] + red[6];
  ss = red[1] + red[3] + red[5] + red[7];
  float mean = s * (1.0f / DIM);
  float var = ss * (1.0f / DIM) - mean * mean;
  float rstd = rsqrtf(var + 1e-5f);
  float4 gv = ((const float4*)g)[t];
  float4 bv = ((const float4*)bb)[t];
  float o0 = (v.x - mean) * rstd * gv.x + bv.x;
  float o1 = (v.y - mean) * rstd * gv.y + bv.y;
  float o2 = (v.z - mean) * rstd * gv.z + bv.z;
  float o3 = (v.w - mean) * rstd * gv.w + bv.w;
  if constexpr (sizeof(OUT_T) == 2) {
    f16x4 h = {(f16)o0, (f16)o1, (f16)o2, (f16)o3};
    *(f16x4*)((f16*)out + (size_t)row * DIM + t * 4) = h;
  } else {
    float4 o = {o0, o1, o2, o3};
    *(float4*)((float*)out + (size_t)row * DIM + t * 4) = o;
  }
}

// ---- NT GEMM: A f16 [M][K], Bt f16 [N][K], C = A*Bt^T. 128x128 tile, BK=64 ----
// XCD-aware block swizzle (gridDim.x always % 8 == 0 at our shapes).
template <bool OUT_F32>
__global__ __launch_bounds__(256, 2) void gemm_nt_kernel(
    const f16* __restrict__ A, const f16* __restrict__ Bt, void* __restrict__ C,
    int M, int N, int K) {
  __shared__ f16 As[128 * 64];
  __shared__ f16 Bs[128 * 64];
  int nb = N >> 7;
  int cpx = gridDim.x >> 3;
  int wg = ((int)blockIdx.x & 7) * cpx + ((int)blockIdx.x >> 3);
  int bm = wg / nb, bn = wg % nb;
  int t = threadIdx.x;
  int lane = t & 63, w = t >> 6;
  int wm = w >> 1, wn = w & 1;       // 2x2 wave grid, each wave 64x64 output
  int r16 = lane & 15, g4 = lane >> 4;
  f32x4 acc[4][4] = {};
  for (int k0 = 0; k0 < K; k0 += 64) {
    // stage A,B tiles: [128 rows][64 k] f16, 16B chunks. LDS dest is LINEAR
    // (global_load_lds constraint); the global SOURCE is pre-swizzled
    // (chunk c -> c ^ (row&7)) so the ds_read side can XOR-swizzle (rule #21).
#pragma unroll
    for (int i = 0; i < 4; ++i) {
      int li = i * 256 + t;          // 0..1023 16B chunks
      int r = li >> 3, c = li & 7;
      int kc = ((c ^ (r & 7)) << 3); // element offset of swizzled chunk
      gload_lds16(A + (size_t)(bm * 128 + r) * K + k0 + kc, (char*)As + li * 16);
      gload_lds16(Bt + (size_t)(bn * 128 + r) * K + k0 + kc, (char*)Bs + li * 16);
    }
    asm volatile("s_waitcnt vmcnt(0)" ::: "memory");
    __syncthreads();
#pragma unroll
    for (int ks = 0; ks < 2; ++ks) {
      f16x8 af[4], bf[4];
#pragma unroll
      for (int mi = 0; mi < 4; ++mi) {
        int r = wm * 64 + mi * 16 + r16;
        int cidx = ks * 4 + g4;
        af[mi] = *(const f16x8*)(As + r * 64 + ((cidx ^ (r & 7)) << 3));
      }
#pragma unroll
      for (int ni = 0; ni < 4; ++ni) {
        int r = wn * 64 + ni * 16 + r16;
        int cidx = ks * 4 + g4;
        bf[ni] = *(const f16x8*)(Bs + r * 64 + ((cidx ^ (r & 7)) << 3));
      }
#pragma unroll
      for (int mi = 0; mi < 4; ++mi)
#pragma unroll
        for (int ni = 0; ni < 4; ++ni)
          acc[mi][ni] = __builtin_amdgcn_mfma_f32_16x16x32_f16(af[mi], bf[ni],
                                                               acc[mi][ni], 0, 0, 0);
    }
    __syncthreads();
  }
  // epilogue: C/D layout col = lane&15, row = (lane>>4)*4 + reg
  int cr0 = bm * 128 + wm * 64;
  int cc = bn * 128 + wn * 64 + r16;
#pragma unroll
  for (int mi = 0; mi < 4; ++mi)
#pragma unroll
    for (int ni = 0; ni < 4; ++ni)
#pragma unroll
      for (int j = 0; j < 4; ++j) {
        int row = cr0 + mi * 16 + g4 * 4 + j;
        int col = cc + ni * 16;
        if constexpr (OUT_F32)
          ((float*)C)[(size_t)row * N + col] = acc[mi][ni][j];
        else
          ((f16*)C)[(size_t)row * N + col] = (f16)acc[mi][ni][j];
      }
}

// ---- build K [bh][288][64] (l2-norm * k_scale, null@256, zeros 257..287)
//      and V^T [bh][64][288] with keys PERMUTED within each 32-group:
//      key kk -> col 2*(kk&15) + (kk>>4), matching the packed-P k-slot order.
__global__ void prep_kv_kernel(const f16* __restrict__ kv, const float* __restrict__ nullkv,
                               const float* __restrict__ ks, f16* __restrict__ Karr,
                               f16* __restrict__ Varr) {
  int bh = blockIdx.x;           // 64 blocks
  int b = bh >> 4, h = bh & 15;
  int t = threadIdx.x;           // 256
  __shared__ f16 vt[256][65];
  const f16* krow = kv + (size_t)(b * 256 + t) * 2048 + h * 64;
  const f16* vrow = krow + 1024;
  f16x8 kd[8];
  float ss = 0.0f;
#pragma unroll
  for (int i = 0; i < 8; ++i) {
    kd[i] = *(const f16x8*)(krow + i * 8);
#pragma unroll
    for (int j = 0; j < 8; ++j) { float x = (float)kd[i][j]; ss += x * x; }
  }
  float inv = 1.0f / fmaxf(sqrtf(ss), 1e-12f);
  f16* kout = Karr + ((size_t)bh * TKP + t) * 64;
#pragma unroll
  for (int i = 0; i < 8; ++i) {
    f16x8 o;
#pragma unroll
    for (int j = 0; j < 8; ++j) o[j] = (f16)((float)kd[i][j] * inv * ks[i * 8 + j]);
    *(f16x8*)(kout + i * 8) = o;
  }
#pragma unroll
  for (int i = 0; i < 8; ++i) {
    f16x8 vv = *(const f16x8*)(vrow + i * 8);
#pragma unroll
    for (int j = 0; j < 8; ++j) vt[t][i * 8 + j] = vv[j];
  }
  if (t < 32) {   // K rows 256..287
    f16* kr = Karr + ((size_t)bh * TKP + 256 + t) * 64;
    if (t == 0) {
      float ssn = 0.0f;
      for (int d = 0; d < 64; ++d) ssn += nullkv[d] * nullkv[d];
      float invn = 1.0f / fmaxf(sqrtf(ssn), 1e-12f);
      for (int d = 0; d < 64; ++d) kr[d] = (f16)(nullkv[d] * invn * ks[d]);
    } else {
      for (int d = 0; d < 64; ++d) kr[d] = (f16)0.0f;
    }
  }
  __syncthreads();
  f16* vbase = Varr + (size_t)bh * 64 * TKP;
  int pcol = (t & ~31) | (((t & 15) << 1) | ((t >> 4) & 1));  // permuted key col
  for (int d = 0; d < 64; ++d) vbase[(size_t)d * TKP + pcol] = vt[t][d];
#pragma unroll
  for (int i = 0; i < 8; ++i) {      // V keys 256..287 (perm maps 256->256; rest zero)
    int idx = i * 256 + t;
    int d = idx >> 5, key = 256 + (idx & 31);
    vbase[(size_t)d * TKP + key] = (key == 256) ? (f16)nullkv[64 + d] : (f16)0.0f;
  }
}

// ---- flash attention, fixed-bound softmax (Cauchy-Schwarz bound on l2-normed
//      q,k scores), mask folded into exp bias, fdot2 denominator, manual
//      K-prefetch pipeline. 4 waves/block, 32 q-rows/wave, 9x32-key tiles.
__global__ __launch_bounds__(256, 4) void attn_kernel(
    const f16* __restrict__ Q, const f16* __restrict__ Karr,
    const f16* __restrict__ Varr, const float* __restrict__ qs,
    const float* __restrict__ ksc, f16* __restrict__ O) {
  // chunked XCD swizzle: 2048 blocks -> 256 contiguous per XCD (8 heads' K/V per L2)
  int wgid = ((int)blockIdx.x & 7) * 256 + ((int)blockIdx.x >> 3);
  int qb = wgid & 31, bh = wgid >> 5;
  int b = bh >> 4, h = bh & 15;
  int t = threadIdx.x, lane = t & 63, w = t >> 6;
  int r16 = lane & 15, g4 = lane >> 4;
  int row0 = b * N_ + qb * 128 + w * 32;
  int col0 = h * 64;
  const f16* Kp = Karr + (size_t)bh * TKP * 64;
  const f16* Vp = Varr + (size_t)bh * 64 * TKP;
  __shared__ f16 Plds[4][32 * 40];   // per-wave P buffer [32 rows][40 (32 used)]
  f16* Pw = &Plds[w][0];
  // score bound M = SCALE * max|qs| * max|ks|  (==8 for unit scales)
  float mq = fabsf(qs[lane]), mk = fabsf(ksc[lane]);
#pragma unroll
  for (int m = 1; m < 64; m <<= 1) {
    mq = fmaxf(mq, __shfl_xor(mq, m));
    mk = fmaxf(mk, __shfl_xor(mk, m));
  }
  const float c1 = SCALE_ * LOG2E;
  const float c2 = SCALE_ * mq * mk * LOG2E;
  // Q fragments with fused l2-norm * q_scale
  float qsv[2][8];
#pragma unroll
  for (int kdh = 0; kdh < 2; ++kdh)
#pragma unroll
    for (int i = 0; i < 8; ++i) qsv[kdh][i] = qs[kdh * 32 + g4 * 8 + i];
  f16x8 qf[2][2];
#pragma unroll
  for (int mi = 0; mi < 2; ++mi) {
    float f[2][8];
    float ssq = 0.0f;
#pragma unroll
    for (int kdh = 0; kdh < 2; ++kdh) {
      f16x8 v = *(const f16x8*)(Q + (size_t)(row0 + mi * 16 + r16) * DIM +
                                col0 + kdh * 32 + g4 * 8);
#pragma unroll
      for (int i = 0; i < 8; ++i) { f[kdh][i] = (float)v[i]; ssq += f[kdh][i] * f[kdh][i]; }
    }
    ssq += __shfl_xor(ssq, 16);
    ssq += __shfl_xor(ssq, 32);
    float inv = 1.0f / fmaxf(sqrtf(ssq), 1e-12f);
#pragma unroll
    for (int kdh = 0; kdh < 2; ++kdh) {
      f16x8 o;
#pragma unroll
      for (int i = 0; i < 8; ++i) o[i] = (f16)(f[kdh][i] * inv * qsv[kdh][i]);
      qf[mi][kdh] = o;
    }
  }
  f32x4 o[2][4] = {};
  float part[2][4] = {};   // per-lane partial softmax denominators (f32 via fdot2)
  const h16x2 ones2 = {(__fp16)1.0f, (__fp16)1.0f};
  // prologue: load K fragments for tile 0
  f16x8 kf[2][2];
#pragma unroll
  for (int ni = 0; ni < 2; ++ni)
#pragma unroll
    for (int kdh = 0; kdh < 2; ++kdh)
      kf[ni][kdh] = *(const f16x8*)(Kp + (size_t)(ni * 16 + r16) * 64 +
                                    kdh * 32 + g4 * 8);
  for (int kt = 0; kt < 9; ++kt) {
    int key0 = kt * 32;
    // issue V loads for this tile early (latency hides under QK + softmax)
    f16x8 vf[4];
#pragma unroll
    for (int nd = 0; nd < 4; ++nd)
      vf[nd] = *(const f16x8*)(Vp + (size_t)(nd * 16 + r16) * TKP + key0 + g4 * 8);
    // per-tile exp bias: invalid keys get -128 -> exp2 underflows to 0
    float nb0 = (key0 + r16 <= 256) ? -c2 : -(c2 + 128.0f);
    float nb1 = (key0 + 16 + r16 <= 256) ? -c2 : -(c2 + 128.0f);
    f32x4 s[2][2] = {};
    __builtin_amdgcn_s_setprio(1);
#pragma unroll
    for (int kdh = 0; kdh < 2; ++kdh)
#pragma unroll
      for (int mi = 0; mi < 2; ++mi)
#pragma unroll
        for (int ni = 0; ni < 2; ++ni)
          s[mi][ni] = __builtin_amdgcn_mfma_f32_16x16x32_f16(qf[mi][kdh], kf[ni][kdh],
                                                             s[mi][ni], 0, 0, 0);
    __builtin_amdgcn_s_setprio(0);
    // prefetch next tile's K fragments (compiler renames kf -> implicit dbuf;
    // L2 latency hides under softmax + PV below)
    if (kt < 8) {
#pragma unroll
      for (int ni = 0; ni < 2; ++ni)
#pragma unroll
        for (int kdh = 0; kdh < 2; ++kdh)
          kf[ni][kdh] = *(const f16x8*)(Kp + (size_t)(key0 + 32 + ni * 16 + r16) * 64 +
                                        kdh * 32 + g4 * 8);
    }
    // softmax: p = exp2(s*c1 + nb); pack pair -> one b32 LDS write;
    // denominator via v_dot2_f32_f16 on the packed (f16-consistent) pair.
#pragma unroll
    for (int mi = 0; mi < 2; ++mi) {
#pragma unroll
      for (int j = 0; j < 4; ++j) {
        float p0 = __builtin_amdgcn_exp2f(s[mi][0][j] * c1 + nb0);
        float p1 = __builtin_amdgcn_exp2f(s[mi][1][j] * c1 + nb1);
        h16x2 pk = __builtin_amdgcn_cvt_pkrtz(p0, p1);
        part[mi][j] = __builtin_amdgcn_fdot2(pk, ones2, part[mi][j], false);
        int prow = mi * 16 + g4 * 4 + j;
        ((uint32_t*)(Pw + prow * 40))[r16] = __builtin_bit_cast(uint32_t, pk);
      }
    }
    __builtin_amdgcn_s_setprio(1);
#pragma unroll
    for (int mi = 0; mi < 2; ++mi) {
      f16x8 pa = *(const f16x8*)(Pw + (mi * 16 + r16) * 40 + g4 * 8);
#pragma unroll
      for (int nd = 0; nd < 4; ++nd)
        o[mi][nd] = __builtin_amdgcn_mfma_f32_16x16x32_f16(pa, vf[nd], o[mi][nd], 0, 0, 0);
    }
    __builtin_amdgcn_s_setprio(0);
  }
  // one deferred row-sum reduction (across the 16 r16 lanes)
#pragma unroll
  for (int mi = 0; mi < 2; ++mi)
#pragma unroll
    for (int j = 0; j < 4; ++j) {
      float v = part[mi][j];
      v += __shfl_xor(v, 1); v += __shfl_xor(v, 2);
      v += __shfl_xor(v, 4); v += __shfl_xor(v, 8);
      part[mi][j] = v;
    }
#pragma unroll
  for (int mi = 0; mi < 2; ++mi)
#pragma unroll
    for (int j = 0; j < 4; ++j) {
      float inv = 1.0f / part[mi][j];
      int row = row0 + mi * 16 + g4 * 4 + j;
#pragma unroll
      for (int nd = 0; nd < 4; ++nd)
        O[(size_t)row * DIM + col0 + nd * 16 + r16] = (f16)(o[mi][nd][j] * inv);
    }
}

extern "C" void kernel_launch(void* const* d_in, const int* in_sizes, int n_in,
                              void* d_out, int out_size, void* d_ws, size_t ws_size,
                              hipStream_t stream) {
  const float* x      = (const float*)d_in[0];
  const float* ctx    = (const float*)d_in[1];
  const float* Wq     = (const float*)d_in[2];
  const float* Wkv    = (const float*)d_in[3];
  const float* Wo     = (const float*)d_in[4];
  const float* nullkv = (const float*)d_in[5];
  const float* qs     = (const float*)d_in[6];
  const float* ks     = (const float*)d_in[7];
  const float* g_in   = (const float*)d_in[8];
  const float* b_in   = (const float*)d_in[9];
  const float* g_ctx  = (const float*)d_in[10];
  const float* b_ctx  = (const float*)d_in[11];
  const float* g_out  = (const float*)d_in[12];
  const float* b_out  = (const float*)d_in[13];

  // Workspace plan (peak ~84 MB):
  //   wqT 0-2, wkvT 2-6, woT 6-8            (live: whole run)
  //   karr 8-11, varr 11-14                 (prep_kv -> attn)
  //   cn 14-16, kvb 16-20
  //   xn 20-52 (ln x -> gemm q)             q_raw 52-84 (gemm q -> attn)
  //   aout 20-52 (attn -> gemm o; overlays dead xn)
  //   out2h 52-84 f16 (gemm o -> ln out; overlays dead q_raw)
  char* ws = (char*)d_ws;
  const size_t MB = 1ull << 20;
  f16* wqT   = (f16*)(ws + 0);
  f16* wkvT  = (f16*)(ws + 2 * MB);
  f16* woT   = (f16*)(ws + 6 * MB);
  f16* karr  = (f16*)(ws + 8 * MB);
  f16* varr  = (f16*)(ws + 11 * MB);
  f16* cn    = (f16*)(ws + 14 * MB);
  f16* kvb   = (f16*)(ws + 16 * MB);
  f16* xn    = (f16*)(ws + 20 * MB);
  f16* q_raw = (f16*)(ws + 52 * MB);
  f16* aout  = (f16*)(ws + 20 * MB);
  f16* out2h = (f16*)(ws + 52 * MB);

  transpose_w_kernel<<<1024, 256, 0, stream>>>(Wq, wqT, 1024, 1024);
  transpose_w_kernel<<<2048, 256, 0, stream>>>(Wkv, wkvT, 1024, 2048);
  transpose_w_kernel<<<1024, 256, 0, stream>>>(Wo, woT, 1024, 1024);

  ln_kernel<float, f16><<<16384, 256, 0, stream>>>(x, g_in, b_in, xn);
  ln_kernel<float, f16><<<1024, 256, 0, stream>>>(ctx, g_ctx, b_ctx, cn);

  gemm_nt_kernel<false><<<(16384 / 128) * (1024 / 128), 256, 0, stream>>>(
      xn, wqT, (void*)q_raw, 16384, 1024, 1024);
  gemm_nt_kernel<false><<<(1024 / 128) * (2048 / 128), 256, 0, stream>>>(
      cn, wkvT, (void*)kvb, 1024, 2048, 1024);

  prep_kv_kernel<<<64, 256, 0, stream>>>(kvb, nullkv, ks, karr, varr);

  attn_kernel<<<2048, 256, 0, stream>>>(q_raw, karr, varr, qs, ks, aout);

  gemm_nt_kernel<false><<<(16384 / 128) * (1024 / 128), 256, 0, stream>>>(
      aout, woT, (void*)out2h, 16384, 1024, 1024);

  ln_kernel<f16, float><<<16384, 256, 0, stream>>>(out2h, g_out, b_out, (float*)d_out);
}

// Round 6
// 330.160 us; speedup vs baseline: 1.2242x; 1.0284x over previous
//
#include <hip/hip_runtime.h>
#include <cstdint>
#include <cstddef>

typedef _Float16 f16;
typedef _Float16 f16x4 __attribute__((ext_vector_type(4)));
typedef _Float16 f16x8 __attribute__((ext_vector_type(8)));
typedef float f32x4 __attribute__((ext_vector_type(4)));
typedef __fp16 h16x2 __attribute__((ext_vector_type(2)));

#define DIM 1024
#define B_ 4
#define N_ 4096
#define TKP 288           // padded key count (256 tokens + null + pad to 9*32)
#define SCALE_ 8.0f
#define LOG2E 1.4426950408889634f

// ---- async global->LDS, 16B per lane (CK-style addrspace casts) ----
__device__ __forceinline__ void gload_lds16(const void* g, void* l) {
  __builtin_amdgcn_global_load_lds(
      reinterpret_cast<const __attribute__((address_space(1))) uint32_t*>(
          reinterpret_cast<uintptr_t>(g)),
      reinterpret_cast<__attribute__((address_space(3))) uint32_t*>(
          reinterpret_cast<uintptr_t>(l)),
      16, 0, 0);
}

// ---- merged weight transposes: W fp32 [K][N] -> WT f16 [N][K] for Wq/Wkv/Wo ----
__global__ void transpose_all_kernel(const float* __restrict__ Wq,
                                     const float* __restrict__ Wkv,
                                     const float* __restrict__ Wo,
                                     f16* __restrict__ wqT, f16* __restrict__ wkvT,
                                     f16* __restrict__ woT) {
  int bid = blockIdx.x;            // 0..4095
  const float* W; f16* WT; int K = 1024, N; int tb;
  if (bid < 1024)      { W = Wq;  WT = wqT;  N = 1024; tb = bid; }
  else if (bid < 3072) { W = Wkv; WT = wkvT; N = 2048; tb = bid - 1024; }
  else                 { W = Wo;  WT = woT;  N = 1024; tb = bid - 3072; }
  __shared__ float tile[32][33];
  int nt = N >> 5;
  int tk = tb / nt, tn = tb % nt;
  int tx = threadIdx.x & 31, ty = threadIdx.x >> 5;  // 256 thr: ty 0..7
#pragma unroll
  for (int p = 0; p < 32; p += 8)
    tile[ty + p][tx] = W[(size_t)(tk * 32 + ty + p) * N + tn * 32 + tx];
  __syncthreads();
#pragma unroll
  for (int p = 0; p < 32; p += 8)
    WT[(size_t)(tn * 32 + ty + p) * K + tk * 32 + tx] = (f16)tile[tx][ty + p];
}

// ---- LayerNorm body over 1024 ----
__device__ __forceinline__ void ln_row_f16out(const float4 v, const float* g,
                                              const float* bb, int t, f16* outrow) {
  float s = v.x + v.y + v.z + v.w;
  float ss = v.x * v.x + v.y * v.y + v.z * v.z + v.w * v.w;
#pragma unroll
  for (int m = 1; m < 64; m <<= 1) { s += __shfl_xor(s, m); ss += __shfl_xor(ss, m); }
  __shared__ float red[8];
  int w = t >> 6;
  if ((t & 63) == 0) { red[w * 2] = s; red[w * 2 + 1] = ss; }
  __syncthreads();
  s = red[0] + red[2] + red[4] + red[6];
  ss = red[1] + red[3] + red[5] + red[7];
  float mean = s * (1.0f / DIM);
  float var = ss * (1.0f / DIM) - mean * mean;
  float rstd = rsqrtf(var + 1e-5f);
  float4 gv = ((const float4*)g)[t];
  float4 bv = ((const float4*)bb)[t];
  f16x4 h = {(f16)((v.x - mean) * rstd * gv.x + bv.x),
             (f16)((v.y - mean) * rstd * gv.y + bv.y),
             (f16)((v.z - mean) * rstd * gv.z + bv.z),
             (f16)((v.w - mean) * rstd * gv.w + bv.w)};
  *(f16x4*)(outrow + t * 4) = h;
}

// merged LN for x (16384 rows) and ctx (1024 rows), f32 in -> f16 out
__global__ void ln_xc_kernel(const float* __restrict__ x, const float* __restrict__ ctx,
                             const float* __restrict__ gx, const float* __restrict__ bx,
                             const float* __restrict__ gc, const float* __restrict__ bc,
                             f16* __restrict__ xn, f16* __restrict__ cn) {
  int row = blockIdx.x;
  int t = threadIdx.x;
  const float* in; const float* g; const float* bb; f16* out; int r;
  if (row < 16384) { in = x; g = gx; bb = bx; out = xn; r = row; }
  else             { in = ctx; g = gc; bb = bc; out = cn; r = row - 16384; }
  float4 v = ((const float4*)(in + (size_t)r * DIM))[t];
  ln_row_f16out(v, g, bb, t, out + (size_t)r * DIM);
}

// final LN: f16 in -> f32 out
__global__ void ln_out_kernel(const f16* __restrict__ in, const float* __restrict__ g,
                              const float* __restrict__ bb, float* __restrict__ out) {
  int row = blockIdx.x;
  int t = threadIdx.x;
  f16x4 h = ((const f16x4*)(in + (size_t)row * DIM))[t];
  float4 v = {(float)h[0], (float)h[1], (float)h[2], (float)h[3]};
  float s = v.x + v.y + v.z + v.w;
  float ss = v.x * v.x + v.y * v.y + v.z * v.z + v.w * v.w;
#pragma unroll
  for (int m = 1; m < 64; m <<= 1) { s += __shfl_xor(s, m); ss += __shfl_xor(ss, m); }
  __shared__ float red[8];
  int w = t >> 6;
  if ((t & 63) == 0) { red[w * 2] = s; red[w * 2 + 1] = ss; }
  __syncthreads();
  s = red[0] + red[2] + red[4] + red[6];
  ss = red[1] + red[3] + red[5] + red[7];
  float mean = s * (1.0f / DIM);
  float var = ss * (1.0f / DIM) - mean * mean;
  float rstd = rsqrtf(var + 1e-5f);
  float4 gv = ((const float4*)g)[t];
  float4 bv = ((const float4*)bb)[t];
  float4 o = {(v.x - mean) * rstd * gv.x + bv.x, (v.y - mean) * rstd * gv.y + bv.y,
              (v.z - mean) * rstd * gv.z + bv.z, (v.w - mean) * rstd * gv.w + bv.w};
  *(float4*)(out + (size_t)row * DIM + t * 4) = o;
}

// ---- NT GEMM: A f16 [M][K], Bt f16 [N][K], C = A*Bt^T. 128x128 tile, BK=64 ----
template <bool OUT_F32>
__global__ __launch_bounds__(256, 2) void gemm_nt_kernel(
    const f16* __restrict__ A, const f16* __restrict__ Bt, void* __restrict__ C,
    int M, int N, int K) {
  __shared__ f16 As[128 * 64];
  __shared__ f16 Bs[128 * 64];
  int nb = N >> 7;
  int cpx = gridDim.x >> 3;
  int wg = ((int)blockIdx.x & 7) * cpx + ((int)blockIdx.x >> 3);
  int bm = wg / nb, bn = wg % nb;
  int t = threadIdx.x;
  int lane = t & 63, w = t >> 6;
  int wm = w >> 1, wn = w & 1;       // 2x2 wave grid, each wave 64x64 output
  int r16 = lane & 15, g4 = lane >> 4;
  f32x4 acc[4][4] = {};
  for (int k0 = 0; k0 < K; k0 += 64) {
#pragma unroll
    for (int i = 0; i < 4; ++i) {
      int li = i * 256 + t;          // 0..1023 16B chunks
      int r = li >> 3, c = li & 7;
      int kc = ((c ^ (r & 7)) << 3); // element offset of swizzled chunk
      gload_lds16(A + (size_t)(bm * 128 + r) * K + k0 + kc, (char*)As + li * 16);
      gload_lds16(Bt + (size_t)(bn * 128 + r) * K + k0 + kc, (char*)Bs + li * 16);
    }
    __syncthreads();
#pragma unroll
    for (int ks = 0; ks < 2; ++ks) {
      f16x8 af[4], bf[4];
#pragma unroll
      for (int mi = 0; mi < 4; ++mi) {
        int r = wm * 64 + mi * 16 + r16;
        int cidx = ks * 4 + g4;
        af[mi] = *(const f16x8*)(As + r * 64 + ((cidx ^ (r & 7)) << 3));
      }
#pragma unroll
      for (int ni = 0; ni < 4; ++ni) {
        int r = wn * 64 + ni * 16 + r16;
        int cidx = ks * 4 + g4;
        bf[ni] = *(const f16x8*)(Bs + r * 64 + ((cidx ^ (r & 7)) << 3));
      }
#pragma unroll
      for (int mi = 0; mi < 4; ++mi)
#pragma unroll
        for (int ni = 0; ni < 4; ++ni)
          acc[mi][ni] = __builtin_amdgcn_mfma_f32_16x16x32_f16(af[mi], bf[ni],
                                                               acc[mi][ni], 0, 0, 0);
    }
    __syncthreads();
  }
  int cr0 = bm * 128 + wm * 64;
  int cc = bn * 128 + wn * 64 + r16;
#pragma unroll
  for (int mi = 0; mi < 4; ++mi)
#pragma unroll
    for (int ni = 0; ni < 4; ++ni)
#pragma unroll
      for (int j = 0; j < 4; ++j) {
        int row = cr0 + mi * 16 + g4 * 4 + j;
        int col = cc + ni * 16;
        if constexpr (OUT_F32)
          ((float*)C)[(size_t)row * N + col] = acc[mi][ni][j];
        else
          ((f16*)C)[(size_t)row * N + col] = (f16)acc[mi][ni][j];
      }
}

// ---- build K [bh][288][64] (l2-norm * k_scale, null@256, zeros 257..287)
//      and V^T [bh][64][288] with keys PERMUTED within each 32-group:
//      key kk -> col 2*(kk&15) + (kk>>4), matching the packed-P k-slot order.
__global__ void prep_kv_kernel(const f16* __restrict__ kv, const float* __restrict__ nullkv,
                               const float* __restrict__ ks, f16* __restrict__ Karr,
                               f16* __restrict__ Varr) {
  int bh = blockIdx.x;           // 64 blocks
  int b = bh >> 4, h = bh & 15;
  int t = threadIdx.x;           // 256
  __shared__ f16 vt[256][65];
  const f16* krow = kv + (size_t)(b * 256 + t) * 2048 + h * 64;
  const f16* vrow = krow + 1024;
  f16x8 kd[8];
  float ss = 0.0f;
#pragma unroll
  for (int i = 0; i < 8; ++i) {
    kd[i] = *(const f16x8*)(krow + i * 8);
#pragma unroll
    for (int j = 0; j < 8; ++j) { float x = (float)kd[i][j]; ss += x * x; }
  }
  float inv = 1.0f / fmaxf(sqrtf(ss), 1e-12f);
  f16* kout = Karr + ((size_t)bh * TKP + t) * 64;
#pragma unroll
  for (int i = 0; i < 8; ++i) {
    f16x8 o;
#pragma unroll
    for (int j = 0; j < 8; ++j) o[j] = (f16)((float)kd[i][j] * inv * ks[i * 8 + j]);
    *(f16x8*)(kout + i * 8) = o;
  }
#pragma unroll
  for (int i = 0; i < 8; ++i) {
    f16x8 vv = *(const f16x8*)(vrow + i * 8);
#pragma unroll
    for (int j = 0; j < 8; ++j) vt[t][i * 8 + j] = vv[j];
  }
  if (t < 32) {   // K rows 256..287
    f16* kr = Karr + ((size_t)bh * TKP + 256 + t) * 64;
    if (t == 0) {
      float ssn = 0.0f;
      for (int d = 0; d < 64; ++d) ssn += nullkv[d] * nullkv[d];
      float invn = 1.0f / fmaxf(sqrtf(ssn), 1e-12f);
      for (int d = 0; d < 64; ++d) kr[d] = (f16)(nullkv[d] * invn * ks[d]);
    } else {
      for (int d = 0; d < 64; ++d) kr[d] = (f16)0.0f;
    }
  }
  __syncthreads();
  f16* vbase = Varr + (size_t)bh * 64 * TKP;
  int pcol = (t & ~31) | (((t & 15) << 1) | ((t >> 4) & 1));  // permuted key col
  for (int d = 0; d < 64; ++d) vbase[(size_t)d * TKP + pcol] = vt[t][d];
#pragma unroll
  for (int i = 0; i < 8; ++i) {      // V keys 256..287 (perm maps 256->256; rest zero)
    int idx = i * 256 + t;
    int d = idx >> 5, key = 256 + (idx & 31);
    vbase[(size_t)d * TKP + key] = (key == 256) ? (f16)nullkv[64 + d] : (f16)0.0f;
  }
}

// ---- flash attention, fixed-bound softmax + block-level double-buffered LDS
//      staging of K/V tiles via global_load_lds (issued a full tile ahead).
//      4 waves/block, 32 q-rows/wave (128 rows/block), 9 x 32-key tiles.
__global__ __launch_bounds__(256, 4) void attn_kernel(
    const f16* __restrict__ Q, const f16* __restrict__ Karr,
    const f16* __restrict__ Varr, const float* __restrict__ qs,
    const float* __restrict__ ksc, f16* __restrict__ O) {
  // chunked XCD swizzle: 2048 blocks -> 256 contiguous per XCD (8 heads' K/V per L2)
  int wgid = ((int)blockIdx.x & 7) * 256 + ((int)blockIdx.x >> 3);
  int qb = wgid & 31, bh = wgid >> 5;
  int b = bh >> 4, h = bh & 15;
  int t = threadIdx.x, lane = t & 63, w = t >> 6;
  int r16 = lane & 15, g4 = lane >> 4;
  int row0 = b * N_ + qb * 128 + w * 32;
  int col0 = h * 64;
  const f16* Kp = Karr + (size_t)bh * TKP * 64;
  const f16* Vp = Varr + (size_t)bh * 64 * TKP;
  __shared__ f16 Ks[2][32 * 64];     // 4 KB per buffer, [key][d]
  __shared__ f16 Vs[2][64 * 32];     // 4 KB per buffer, [d][key(permuted)]
  __shared__ f16 Plds[4][32 * 40];   // per-wave P buffer [32 rows][40 (32 used)]
  f16* Pw = &Plds[w][0];
  // staging index precompute (per thread, all tiles):
  // K tile: thread t covers LDS bytes t*16 -> row t/8, chunk t%8; source chunk
  // XOR-swizzled so ds_read side is conflict-free (rule #21).
  int krow_s = t >> 3;
  int kc_s = (t & 7) ^ (krow_s & 7);
  int vrow_s = t >> 2;
  int vc_s = (t & 3) ^ ((vrow_s >> 1) & 3);
  // score bound M = SCALE * max|qs| * max|ks|  (==8 for unit scales)
  float mq = fabsf(qs[lane]), mk = fabsf(ksc[lane]);
#pragma unroll
  for (int m = 1; m < 64; m <<= 1) {
    mq = fmaxf(mq, __shfl_xor(mq, m));
    mk = fmaxf(mk, __shfl_xor(mk, m));
  }
  const float c1 = SCALE_ * LOG2E;
  const float c2 = SCALE_ * mq * mk * LOG2E;
  // stage tile 0 into buffer 0
  gload_lds16(Kp + (size_t)krow_s * 64 + kc_s * 8, (char*)Ks[0] + t * 16);
  gload_lds16(Vp + (size_t)vrow_s * TKP + 0 + vc_s * 8, (char*)Vs[0] + t * 16);
  // Q fragments with fused l2-norm * q_scale (overlaps with staging latency)
  float qsv[2][8];
#pragma unroll
  for (int kdh = 0; kdh < 2; ++kdh)
#pragma unroll
    for (int i = 0; i < 8; ++i) qsv[kdh][i] = qs[kdh * 32 + g4 * 8 + i];
  f16x8 qf[2][2];
#pragma unroll
  for (int mi = 0; mi < 2; ++mi) {
    float f[2][8];
    float ssq = 0.0f;
#pragma unroll
    for (int kdh = 0; kdh < 2; ++kdh) {
      f16x8 v = *(const f16x8*)(Q + (size_t)(row0 + mi * 16 + r16) * DIM +
                                col0 + kdh * 32 + g4 * 8);
#pragma unroll
      for (int i = 0; i < 8; ++i) { f[kdh][i] = (float)v[i]; ssq += f[kdh][i] * f[kdh][i]; }
    }
    ssq += __shfl_xor(ssq, 16);
    ssq += __shfl_xor(ssq, 32);
    float inv = 1.0f / fmaxf(sqrtf(ssq), 1e-12f);
#pragma unroll
    for (int kdh = 0; kdh < 2; ++kdh) {
      f16x8 o;
#pragma unroll
      for (int i = 0; i < 8; ++i) o[i] = (f16)(f[kdh][i] * inv * qsv[kdh][i]);
      qf[mi][kdh] = o;
    }
  }
  f32x4 o[2][4] = {};
  float part[2][4] = {};   // per-lane partial softmax denominators
  const h16x2 ones2 = {(__fp16)1.0f, (__fp16)1.0f};
  __syncthreads();          // tile-0 staging complete (syncthreads drains vmcnt)
#pragma unroll
  for (int kt = 0; kt < 9; ++kt) {
    const int cur = kt & 1;
    const int key0 = kt * 32;
    // issue next tile's staging immediately (hidden under this tile's compute)
    if (kt < 8) {
      const int nxt = key0 + 32;
      gload_lds16(Kp + (size_t)(nxt + krow_s) * 64 + kc_s * 8,
                  (char*)Ks[cur ^ 1] + t * 16);
      gload_lds16(Vp + (size_t)vrow_s * TKP + nxt + vc_s * 8,
                  (char*)Vs[cur ^ 1] + t * 16);
    }
    // K fragments from LDS (XOR-swizzled, 2-way max = free)
    f16x8 kf[2][2];
#pragma unroll
    for (int ni = 0; ni < 2; ++ni)
#pragma unroll
      for (int kdh = 0; kdh < 2; ++kdh) {
        int row = ni * 16 + r16;
        int cidx = kdh * 4 + g4;
        kf[ni][kdh] = *(const f16x8*)(Ks[cur] + row * 64 + ((cidx ^ (row & 7)) << 3));
      }
    f32x4 s[2][2] = {};
    __builtin_amdgcn_s_setprio(1);
#pragma unroll
    for (int kdh = 0; kdh < 2; ++kdh)
#pragma unroll
      for (int mi = 0; mi < 2; ++mi)
#pragma unroll
        for (int ni = 0; ni < 2; ++ni)
          s[mi][ni] = __builtin_amdgcn_mfma_f32_16x16x32_f16(qf[mi][kdh], kf[ni][kdh],
                                                             s[mi][ni], 0, 0, 0);
    __builtin_amdgcn_s_setprio(0);
    // softmax with mask folded into the exp bias (padded keys -> exp2 -> 0)
    float nb0 = (key0 + r16 <= 256) ? -c2 : -(c2 + 128.0f);
    float nb1 = (key0 + 16 + r16 <= 256) ? -c2 : -(c2 + 128.0f);
#pragma unroll
    for (int mi = 0; mi < 2; ++mi) {
#pragma unroll
      for (int j = 0; j < 4; ++j) {
        float p0 = __builtin_amdgcn_exp2f(s[mi][0][j] * c1 + nb0);
        float p1 = __builtin_amdgcn_exp2f(s[mi][1][j] * c1 + nb1);
        h16x2 pk = __builtin_amdgcn_cvt_pkrtz(p0, p1);
        part[mi][j] = __builtin_amdgcn_fdot2(pk, ones2, part[mi][j], false);
        int prow = mi * 16 + g4 * 4 + j;
        ((uint32_t*)(Pw + prow * 40))[r16] = __builtin_bit_cast(uint32_t, pk);
      }
    }
    // V fragments from LDS (swizzled slot, 2-way max = free)
    f16x8 vf[4];
#pragma unroll
    for (int nd = 0; nd < 4; ++nd) {
      int row = nd * 16 + r16;
      int slot = g4 ^ ((row >> 1) & 3);
      vf[nd] = *(const f16x8*)(Vs[cur] + row * 32 + (slot << 3));
    }
    __builtin_amdgcn_s_setprio(1);
#pragma unroll
    for (int mi = 0; mi < 2; ++mi) {
      f16x8 pa = *(const f16x8*)(Pw + (mi * 16 + r16) * 40 + g4 * 8);
#pragma unroll
      for (int nd = 0; nd < 4; ++nd)
        o[mi][nd] = __builtin_amdgcn_mfma_f32_16x16x32_f16(pa, vf[nd], o[mi][nd], 0, 0, 0);
    }
    __builtin_amdgcn_s_setprio(0);
    // staged loads for kt+1 landed (issued a full tile ago); all waves done
    // reading buf[cur]; single barrier per tile is race-free (buf parity).
    __syncthreads();
  }
  // one deferred row-sum reduction (across the 16 r16 lanes)
#pragma unroll
  for (int mi = 0; mi < 2; ++mi)
#pragma unroll
    for (int j = 0; j < 4; ++j) {
      float v = part[mi][j];
      v += __shfl_xor(v, 1); v += __shfl_xor(v, 2);
      v += __shfl_xor(v, 4); v += __shfl_xor(v, 8);
      part[mi][j] = v;
    }
#pragma unroll
  for (int mi = 0; mi < 2; ++mi)
#pragma unroll
    for (int j = 0; j < 4; ++j) {
      float inv = 1.0f / part[mi][j];
      int row = row0 + mi * 16 + g4 * 4 + j;
#pragma unroll
      for (int nd = 0; nd < 4; ++nd)
        O[(size_t)row * DIM + col0 + nd * 16 + r16] = (f16)(o[mi][nd][j] * inv);
    }
}

extern "C" void kernel_launch(void* const* d_in, const int* in_sizes, int n_in,
                              void* d_out, int out_size, void* d_ws, size_t ws_size,
                              hipStream_t stream) {
  const float* x      = (const float*)d_in[0];
  const float* ctx    = (const float*)d_in[1];
  const float* Wq     = (const float*)d_in[2];
  const float* Wkv    = (const float*)d_in[3];
  const float* Wo     = (const float*)d_in[4];
  const float* nullkv = (const float*)d_in[5];
  const float* qs     = (const float*)d_in[6];
  const float* ks     = (const float*)d_in[7];
  const float* g_in   = (const float*)d_in[8];
  const float* b_in   = (const float*)d_in[9];
  const float* g_ctx  = (const float*)d_in[10];
  const float* b_ctx  = (const float*)d_in[11];
  const float* g_out  = (const float*)d_in[12];
  const float* b_out  = (const float*)d_in[13];

  // Workspace plan (peak ~84 MB):
  //   wqT 0-2, wkvT 2-6, woT 6-8            (live: whole run)
  //   karr 8-11, varr 11-14                 (prep_kv -> attn)
  //   cn 14-16, kvb 16-20
  //   xn 20-52 (ln x -> gemm q)             q_raw 52-84 (gemm q -> attn)
  //   aout 20-52 (attn -> gemm o; overlays dead xn)
  //   out2h 52-84 f16 (gemm o -> ln out; overlays dead q_raw)
  char* ws = (char*)d_ws;
  const size_t MB = 1ull << 20;
  f16* wqT   = (f16*)(ws + 0);
  f16* wkvT  = (f16*)(ws + 2 * MB);
  f16* woT   = (f16*)(ws + 6 * MB);
  f16* karr  = (f16*)(ws + 8 * MB);
  f16* varr  = (f16*)(ws + 11 * MB);
  f16* cn    = (f16*)(ws + 14 * MB);
  f16* kvb   = (f16*)(ws + 16 * MB);
  f16* xn    = (f16*)(ws + 20 * MB);
  f16* q_raw = (f16*)(ws + 52 * MB);
  f16* aout  = (f16*)(ws + 20 * MB);
  f16* out2h = (f16*)(ws + 52 * MB);

  transpose_all_kernel<<<4096, 256, 0, stream>>>(Wq, Wkv, Wo, wqT, wkvT, woT);

  ln_xc_kernel<<<16384 + 1024, 256, 0, stream>>>(x, ctx, g_in, b_in, g_ctx, b_ctx,
                                                 xn, cn);

  gemm_nt_kernel<false><<<(16384 / 128) * (1024 / 128), 256, 0, stream>>>(
      xn, wqT, (void*)q_raw, 16384, 1024, 1024);
  gemm_nt_kernel<false><<<(1024 / 128) * (2048 / 128), 256, 0, stream>>>(
      cn, wkvT, (void*)kvb, 1024, 2048, 1024);

  prep_kv_kernel<<<64, 256, 0, stream>>>(kvb, nullkv, ks, karr, varr);

  attn_kernel<<<2048, 256, 0, stream>>>(q_raw, karr, varr, qs, ks, aout);

  gemm_nt_kernel<false><<<(16384 / 128) * (1024 / 128), 256, 0, stream>>>(
      aout, woT, (void*)out2h, 16384, 1024, 1024);

  ln_out_kernel<<<16384, 256, 0, stream>>>(out2h, g_out, b_out, (float*)d_out);
}

// Round 7
// 325.983 us; speedup vs baseline: 1.2399x; 1.0128x over previous
//
#include <hip/hip_runtime.h>
#include <cstdint>
#include <cstddef>

typedef _Float16 f16;
typedef _Float16 f16x4 __attribute__((ext_vector_type(4)));
typedef _Float16 f16x8 __attribute__((ext_vector_type(8)));
typedef float f32x4 __attribute__((ext_vector_type(4)));
typedef __fp16 h16x2 __attribute__((ext_vector_type(2)));

#define DIM 1024
#define B_ 4
#define N_ 4096
#define TKP 288           // padded key count (256 tokens + null + pad to 9*32)
#define SCALE_ 8.0f
#define LOG2E 1.4426950408889634f

// ---- async global->LDS, 16B per lane (CK-style addrspace casts) ----
__device__ __forceinline__ void gload_lds16(const void* g, void* l) {
  __builtin_amdgcn_global_load_lds(
      reinterpret_cast<const __attribute__((address_space(1))) uint32_t*>(
          reinterpret_cast<uintptr_t>(g)),
      reinterpret_cast<__attribute__((address_space(3))) uint32_t*>(
          reinterpret_cast<uintptr_t>(l)),
      16, 0, 0);
}

// ---- merged weight transposes: W fp32 [K][N] -> WT f16 [N][K] for Wq/Wkv/Wo ----
__global__ void transpose_all_kernel(const float* __restrict__ Wq,
                                     const float* __restrict__ Wkv,
                                     const float* __restrict__ Wo,
                                     f16* __restrict__ wqT, f16* __restrict__ wkvT,
                                     f16* __restrict__ woT) {
  int bid = blockIdx.x;            // 0..4095
  const float* W; f16* WT; int K = 1024, N; int tb;
  if (bid < 1024)      { W = Wq;  WT = wqT;  N = 1024; tb = bid; }
  else if (bid < 3072) { W = Wkv; WT = wkvT; N = 2048; tb = bid - 1024; }
  else                 { W = Wo;  WT = woT;  N = 1024; tb = bid - 3072; }
  __shared__ float tile[32][33];
  int nt = N >> 5;
  int tk = tb / nt, tn = tb % nt;
  int tx = threadIdx.x & 31, ty = threadIdx.x >> 5;  // 256 thr: ty 0..7
#pragma unroll
  for (int p = 0; p < 32; p += 8)
    tile[ty + p][tx] = W[(size_t)(tk * 32 + ty + p) * N + tn * 32 + tx];
  __syncthreads();
#pragma unroll
  for (int p = 0; p < 32; p += 8)
    WT[(size_t)(tn * 32 + ty + p) * K + tk * 32 + tx] = (f16)tile[tx][ty + p];
}

// ---- LayerNorm body over 1024 ----
__device__ __forceinline__ void ln_row_f16out(const float4 v, const float* g,
                                              const float* bb, int t, f16* outrow) {
  float s = v.x + v.y + v.z + v.w;
  float ss = v.x * v.x + v.y * v.y + v.z * v.z + v.w * v.w;
#pragma unroll
  for (int m = 1; m < 64; m <<= 1) { s += __shfl_xor(s, m); ss += __shfl_xor(ss, m); }
  __shared__ float red[8];
  int w = t >> 6;
  if ((t & 63) == 0) { red[w * 2] = s; red[w * 2 + 1] = ss; }
  __syncthreads();
  s = red[0] + red[2] + red[4] + red[6];
  ss = red[1] + red[3] + red[5] + red[7];
  float mean = s * (1.0f / DIM);
  float var = ss * (1.0f / DIM) - mean * mean;
  float rstd = rsqrtf(var + 1e-5f);
  float4 gv = ((const float4*)g)[t];
  float4 bv = ((const float4*)bb)[t];
  f16x4 h = {(f16)((v.x - mean) * rstd * gv.x + bv.x),
             (f16)((v.y - mean) * rstd * gv.y + bv.y),
             (f16)((v.z - mean) * rstd * gv.z + bv.z),
             (f16)((v.w - mean) * rstd * gv.w + bv.w)};
  *(f16x4*)(outrow + t * 4) = h;
}

// merged LN for x (16384 rows) and ctx (1024 rows), f32 in -> f16 out
__global__ void ln_xc_kernel(const float* __restrict__ x, const float* __restrict__ ctx,
                             const float* __restrict__ gx, const float* __restrict__ bx,
                             const float* __restrict__ gc, const float* __restrict__ bc,
                             f16* __restrict__ xn, f16* __restrict__ cn) {
  int row = blockIdx.x;
  int t = threadIdx.x;
  const float* in; const float* g; const float* bb; f16* out; int r;
  if (row < 16384) { in = x; g = gx; bb = bx; out = xn; r = row; }
  else             { in = ctx; g = gc; bb = bc; out = cn; r = row - 16384; }
  float4 v = ((const float4*)(in + (size_t)r * DIM))[t];
  ln_row_f16out(v, g, bb, t, out + (size_t)r * DIM);
}

// final LN: f16 in -> f32 out
__global__ void ln_out_kernel(const f16* __restrict__ in, const float* __restrict__ g,
                              const float* __restrict__ bb, float* __restrict__ out) {
  int row = blockIdx.x;
  int t = threadIdx.x;
  f16x4 h = ((const f16x4*)(in + (size_t)row * DIM))[t];
  float4 v = {(float)h[0], (float)h[1], (float)h[2], (float)h[3]};
  float s = v.x + v.y + v.z + v.w;
  float ss = v.x * v.x + v.y * v.y + v.z * v.z + v.w * v.w;
#pragma unroll
  for (int m = 1; m < 64; m <<= 1) { s += __shfl_xor(s, m); ss += __shfl_xor(ss, m); }
  __shared__ float red[8];
  int w = t >> 6;
  if ((t & 63) == 0) { red[w * 2] = s; red[w * 2 + 1] = ss; }
  __syncthreads();
  s = red[0] + red[2] + red[4] + red[6];
  ss = red[1] + red[3] + red[5] + red[7];
  float mean = s * (1.0f / DIM);
  float var = ss * (1.0f / DIM) - mean * mean;
  float rstd = rsqrtf(var + 1e-5f);
  float4 gv = ((const float4*)g)[t];
  float4 bv = ((const float4*)bb)[t];
  float4 o = {(v.x - mean) * rstd * gv.x + bv.x, (v.y - mean) * rstd * gv.y + bv.y,
              (v.z - mean) * rstd * gv.z + bv.z, (v.w - mean) * rstd * gv.w + bv.w};
  *(float4*)(out + (size_t)row * DIM + t * 4) = o;
}

// ---- NT GEMM: A f16 [M][K], Bt f16 [N][K], C = A*Bt^T (f16 out). 128x128 tile.
// NORMQ: fuse per-head (64-col group) row l2-norm * q_scale into the epilogue.
// Each wave's 64-wide output tile spans exactly one head (64-aligned cols).
template <bool NORMQ>
__global__ __launch_bounds__(256, 2) void gemm_nt_kernel(
    const f16* __restrict__ A, const f16* __restrict__ Bt, f16* __restrict__ C,
    const float* __restrict__ qs, int M, int N, int K) {
  __shared__ f16 As[128 * 64];
  __shared__ f16 Bs[128 * 64];
  int nb = N >> 7;
  int cpx = gridDim.x >> 3;
  int wg = ((int)blockIdx.x & 7) * cpx + ((int)blockIdx.x >> 3);
  int bm = wg / nb, bn = wg % nb;
  int t = threadIdx.x;
  int lane = t & 63, w = t >> 6;
  int wm = w >> 1, wn = w & 1;       // 2x2 wave grid, each wave 64x64 output
  int r16 = lane & 15, g4 = lane >> 4;
  f32x4 acc[4][4] = {};
  for (int k0 = 0; k0 < K; k0 += 64) {
#pragma unroll
    for (int i = 0; i < 4; ++i) {
      int li = i * 256 + t;          // 0..1023 16B chunks
      int r = li >> 3, c = li & 7;
      int kc = ((c ^ (r & 7)) << 3); // element offset of swizzled chunk
      gload_lds16(A + (size_t)(bm * 128 + r) * K + k0 + kc, (char*)As + li * 16);
      gload_lds16(Bt + (size_t)(bn * 128 + r) * K + k0 + kc, (char*)Bs + li * 16);
    }
    __syncthreads();
#pragma unroll
    for (int ks = 0; ks < 2; ++ks) {
      f16x8 af[4], bf[4];
#pragma unroll
      for (int mi = 0; mi < 4; ++mi) {
        int r = wm * 64 + mi * 16 + r16;
        int cidx = ks * 4 + g4;
        af[mi] = *(const f16x8*)(As + r * 64 + ((cidx ^ (r & 7)) << 3));
      }
#pragma unroll
      for (int ni = 0; ni < 4; ++ni) {
        int r = wn * 64 + ni * 16 + r16;
        int cidx = ks * 4 + g4;
        bf[ni] = *(const f16x8*)(Bs + r * 64 + ((cidx ^ (r & 7)) << 3));
      }
#pragma unroll
      for (int mi = 0; mi < 4; ++mi)
#pragma unroll
        for (int ni = 0; ni < 4; ++ni)
          acc[mi][ni] = __builtin_amdgcn_mfma_f32_16x16x32_f16(af[mi], bf[ni],
                                                               acc[mi][ni], 0, 0, 0);
    }
    __syncthreads();
  }
  // epilogue: C/D layout col = lane&15, row = (lane>>4)*4 + reg
  int cr0 = bm * 128 + wm * 64;
  int cc = bn * 128 + wn * 64 + r16;
  float qsv[4];
  if constexpr (NORMQ) {
#pragma unroll
    for (int ni = 0; ni < 4; ++ni) qsv[ni] = qs[ni * 16 + r16];  // col % 64
  }
#pragma unroll
  for (int mi = 0; mi < 4; ++mi)
#pragma unroll
    for (int j = 0; j < 4; ++j) {
      float inv = 1.0f;
      if constexpr (NORMQ) {
        float ssq = 0.0f;
#pragma unroll
        for (int ni = 0; ni < 4; ++ni) ssq += acc[mi][ni][j] * acc[mi][ni][j];
        ssq += __shfl_xor(ssq, 1); ssq += __shfl_xor(ssq, 2);
        ssq += __shfl_xor(ssq, 4); ssq += __shfl_xor(ssq, 8);
        inv = 1.0f / fmaxf(sqrtf(ssq), 1e-12f);
      }
      int row = cr0 + mi * 16 + g4 * 4 + j;
#pragma unroll
      for (int ni = 0; ni < 4; ++ni) {
        float v = acc[mi][ni][j];
        if constexpr (NORMQ) v = v * inv * qsv[ni];
        C[(size_t)row * N + cc + ni * 16] = (f16)v;
      }
    }
}

// ---- build K [bh][288][64] (l2-norm * k_scale, null@256, zeros 257..287)
//      and V^T [bh][64][288] with keys PERMUTED within each 32-group:
//      key kk -> col 2*(kk&15) + (kk>>4), matching the packed-P k-slot order.
__global__ void prep_kv_kernel(const f16* __restrict__ kv, const float* __restrict__ nullkv,
                               const float* __restrict__ ks, f16* __restrict__ Karr,
                               f16* __restrict__ Varr) {
  int bh = blockIdx.x;           // 64 blocks
  int b = bh >> 4, h = bh & 15;
  int t = threadIdx.x;           // 256
  __shared__ f16 vt[256][65];
  const f16* krow = kv + (size_t)(b * 256 + t) * 2048 + h * 64;
  const f16* vrow = krow + 1024;
  f16x8 kd[8];
  float ss = 0.0f;
#pragma unroll
  for (int i = 0; i < 8; ++i) {
    kd[i] = *(const f16x8*)(krow + i * 8);
#pragma unroll
    for (int j = 0; j < 8; ++j) { float x = (float)kd[i][j]; ss += x * x; }
  }
  float inv = 1.0f / fmaxf(sqrtf(ss), 1e-12f);
  f16* kout = Karr + ((size_t)bh * TKP + t) * 64;
#pragma unroll
  for (int i = 0; i < 8; ++i) {
    f16x8 o;
#pragma unroll
    for (int j = 0; j < 8; ++j) o[j] = (f16)((float)kd[i][j] * inv * ks[i * 8 + j]);
    *(f16x8*)(kout + i * 8) = o;
  }
#pragma unroll
  for (int i = 0; i < 8; ++i) {
    f16x8 vv = *(const f16x8*)(vrow + i * 8);
#pragma unroll
    for (int j = 0; j < 8; ++j) vt[t][i * 8 + j] = vv[j];
  }
  if (t < 32) {   // K rows 256..287
    f16* kr = Karr + ((size_t)bh * TKP + 256 + t) * 64;
    if (t == 0) {
      float ssn = 0.0f;
      for (int d = 0; d < 64; ++d) ssn += nullkv[d] * nullkv[d];
      float invn = 1.0f / fmaxf(sqrtf(ssn), 1e-12f);
      for (int d = 0; d < 64; ++d) kr[d] = (f16)(nullkv[d] * invn * ks[d]);
    } else {
      for (int d = 0; d < 64; ++d) kr[d] = (f16)0.0f;
    }
  }
  __syncthreads();
  f16* vbase = Varr + (size_t)bh * 64 * TKP;
  int pcol = (t & ~31) | (((t & 15) << 1) | ((t >> 4) & 1));  // permuted key col
  for (int d = 0; d < 64; ++d) vbase[(size_t)d * TKP + pcol] = vt[t][d];
#pragma unroll
  for (int i = 0; i < 8; ++i) {      // V keys 256..287 (perm maps 256->256; rest zero)
    int idx = i * 256 + t;
    int d = idx >> 5, key = 256 + (idx & 31);
    vbase[(size_t)d * TKP + key] = (key == 256) ? (f16)nullkv[64 + d] : (f16)0.0f;
  }
}

// ---- flash attention, fixed-bound softmax + 3-buffer LDS staging issued TWO
//      tiles ahead with counted vmcnt (T3/T4 pattern): barrier never drains
//      the just-issued loads. 4 waves/block, 32 q-rows/wave, 9 x 32-key tiles.
__global__ __launch_bounds__(256, 4) void attn_kernel(
    const f16* __restrict__ Q, const f16* __restrict__ Karr,
    const f16* __restrict__ Varr, const float* __restrict__ qs,
    const float* __restrict__ ksc, f16* __restrict__ O) {
  // chunked XCD swizzle: 2048 blocks -> 256 contiguous per XCD (8 heads' K/V per L2)
  int wgid = ((int)blockIdx.x & 7) * 256 + ((int)blockIdx.x >> 3);
  int qb = wgid & 31, bh = wgid >> 5;
  int b = bh >> 4, h = bh & 15;
  int t = threadIdx.x, lane = t & 63, w = t >> 6;
  int r16 = lane & 15, g4 = lane >> 4;
  int row0 = b * N_ + qb * 128 + w * 32;
  int col0 = h * 64;
  const f16* Kp = Karr + (size_t)bh * TKP * 64;
  const f16* Vp = Varr + (size_t)bh * 64 * TKP;
  __shared__ f16 Ks[3][32 * 64];     // 4 KB per buffer, [key][d]
  __shared__ f16 Vs[3][64 * 32];     // 4 KB per buffer, [d][key(permuted)]
  __shared__ f16 Plds[4][32 * 40];   // per-wave P buffer [32 rows][40 (32 used)]
  f16* Pw = &Plds[w][0];
  // staging indices: thread t covers LDS bytes t*16; source chunk XOR-swizzled
  // so the ds_read side is conflict-free (rule #21).
  int krow_s = t >> 3;
  int kc_s = (t & 7) ^ (krow_s & 7);
  int vrow_s = t >> 2;
  int vc_s = (t & 3) ^ ((vrow_s >> 1) & 3);
  // stage tiles 0 and 1 (2 deep)
  gload_lds16(Kp + (size_t)krow_s * 64 + kc_s * 8, (char*)Ks[0] + t * 16);
  gload_lds16(Vp + (size_t)vrow_s * TKP + 0 + vc_s * 8, (char*)Vs[0] + t * 16);
  gload_lds16(Kp + (size_t)(32 + krow_s) * 64 + kc_s * 8, (char*)Ks[1] + t * 16);
  gload_lds16(Vp + (size_t)vrow_s * TKP + 32 + vc_s * 8, (char*)Vs[1] + t * 16);
  // score bound M = SCALE * max|qs| * max|ks|  (==8 for unit scales)
  float mq = fabsf(qs[lane]), mk = fabsf(ksc[lane]);
#pragma unroll
  for (int m = 1; m < 64; m <<= 1) {
    mq = fmaxf(mq, __shfl_xor(mq, m));
    mk = fmaxf(mk, __shfl_xor(mk, m));
  }
  const float c1 = SCALE_ * LOG2E;
  const float c2 = SCALE_ * mq * mk * LOG2E;
  // Q fragments (already l2-normed * q_scale by gemm_q epilogue)
  f16x8 qf[2][2];
#pragma unroll
  for (int mi = 0; mi < 2; ++mi)
#pragma unroll
    for (int kdh = 0; kdh < 2; ++kdh)
      qf[mi][kdh] = *(const f16x8*)(Q + (size_t)(row0 + mi * 16 + r16) * DIM +
                                    col0 + kdh * 32 + g4 * 8);
  f32x4 o[2][4] = {};
  float part[2][4] = {};   // per-lane partial softmax denominators
  const h16x2 ones2 = {(__fp16)1.0f, (__fp16)1.0f};
  // wait for stage(0) only (the 2 newest outstanding = stage(1) may fly)
  asm volatile("s_waitcnt vmcnt(2)" ::: "memory");
  __builtin_amdgcn_s_barrier();
  __builtin_amdgcn_sched_barrier(0);
#pragma unroll
  for (int kt = 0; kt < 9; ++kt) {
    const int cur = kt % 3;
    const int key0 = kt * 32;
    // issue staging two tiles ahead: buf[(kt+2)%3] == buf[(kt-1)%3], which all
    // waves finished reading before the barrier that ended tile kt-1.
    if (kt < 7) {
      const int nxt = key0 + 64;
      const int nbuf = (kt + 2) % 3;
      gload_lds16(Kp + (size_t)(nxt + krow_s) * 64 + kc_s * 8,
                  (char*)Ks[nbuf] + t * 16);
      gload_lds16(Vp + (size_t)vrow_s * TKP + nxt + vc_s * 8,
                  (char*)Vs[nbuf] + t * 16);
    }
    // K fragments from LDS (XOR-swizzled, 2-way max = free)
    f16x8 kf[2][2];
#pragma unroll
    for (int ni = 0; ni < 2; ++ni)
#pragma unroll
      for (int kdh = 0; kdh < 2; ++kdh) {
        int row = ni * 16 + r16;
        int cidx = kdh * 4 + g4;
        kf[ni][kdh] = *(const f16x8*)(Ks[cur] + row * 64 + ((cidx ^ (row & 7)) << 3));
      }
    f32x4 s[2][2] = {};
    __builtin_amdgcn_s_setprio(1);
#pragma unroll
    for (int kdh = 0; kdh < 2; ++kdh)
#pragma unroll
      for (int mi = 0; mi < 2; ++mi)
#pragma unroll
        for (int ni = 0; ni < 2; ++ni)
          s[mi][ni] = __builtin_amdgcn_mfma_f32_16x16x32_f16(qf[mi][kdh], kf[ni][kdh],
                                                             s[mi][ni], 0, 0, 0);
    __builtin_amdgcn_s_setprio(0);
    // softmax with mask folded into the exp bias (padded keys -> exp2 -> 0)
    float nb0 = (key0 + r16 <= 256) ? -c2 : -(c2 + 128.0f);
    float nb1 = (key0 + 16 + r16 <= 256) ? -c2 : -(c2 + 128.0f);
#pragma unroll
    for (int mi = 0; mi < 2; ++mi) {
#pragma unroll
      for (int j = 0; j < 4; ++j) {
        float p0 = __builtin_amdgcn_exp2f(s[mi][0][j] * c1 + nb0);
        float p1 = __builtin_amdgcn_exp2f(s[mi][1][j] * c1 + nb1);
        h16x2 pk = __builtin_amdgcn_cvt_pkrtz(p0, p1);
        part[mi][j] = __builtin_amdgcn_fdot2(pk, ones2, part[mi][j], false);
        int prow = mi * 16 + g4 * 4 + j;
        ((uint32_t*)(Pw + prow * 40))[r16] = __builtin_bit_cast(uint32_t, pk);
      }
    }
    // V fragments from LDS (swizzled slot, 2-way max = free)
    f16x8 vf[4];
#pragma unroll
    for (int nd = 0; nd < 4; ++nd) {
      int row = nd * 16 + r16;
      int slot = g4 ^ ((row >> 1) & 3);
      vf[nd] = *(const f16x8*)(Vs[cur] + row * 32 + (slot << 3));
    }
    __builtin_amdgcn_s_setprio(1);
#pragma unroll
    for (int mi = 0; mi < 2; ++mi) {
      f16x8 pa = *(const f16x8*)(Pw + (mi * 16 + r16) * 40 + g4 * 8);
#pragma unroll
      for (int nd = 0; nd < 4; ++nd)
        o[mi][nd] = __builtin_amdgcn_mfma_f32_16x16x32_f16(pa, vf[nd], o[mi][nd], 0, 0, 0);
    }
    __builtin_amdgcn_s_setprio(0);
    // end of tile: require stage(kt+1) complete; allow stage(kt+2)'s 2 loads
    // to stay in flight (counted vmcnt — never drain to 0 mid-loop).
    if (kt < 7) {
      asm volatile("s_waitcnt vmcnt(2)" ::: "memory");
      __builtin_amdgcn_s_barrier();
      __builtin_amdgcn_sched_barrier(0);
    } else if (kt == 7) {
      asm volatile("s_waitcnt vmcnt(0)" ::: "memory");
      __builtin_amdgcn_s_barrier();
      __builtin_amdgcn_sched_barrier(0);
    }
  }
  // one deferred row-sum reduction (across the 16 r16 lanes)
#pragma unroll
  for (int mi = 0; mi < 2; ++mi)
#pragma unroll
    for (int j = 0; j < 4; ++j) {
      float v = part[mi][j];
      v += __shfl_xor(v, 1); v += __shfl_xor(v, 2);
      v += __shfl_xor(v, 4); v += __shfl_xor(v, 8);
      part[mi][j] = v;
    }
#pragma unroll
  for (int mi = 0; mi < 2; ++mi)
#pragma unroll
    for (int j = 0; j < 4; ++j) {
      float inv = 1.0f / part[mi][j];
      int row = row0 + mi * 16 + g4 * 4 + j;
#pragma unroll
      for (int nd = 0; nd < 4; ++nd)
        O[(size_t)row * DIM + col0 + nd * 16 + r16] = (f16)(o[mi][nd][j] * inv);
    }
}

extern "C" void kernel_launch(void* const* d_in, const int* in_sizes, int n_in,
                              void* d_out, int out_size, void* d_ws, size_t ws_size,
                              hipStream_t stream) {
  const float* x      = (const float*)d_in[0];
  const float* ctx    = (const float*)d_in[1];
  const float* Wq     = (const float*)d_in[2];
  const float* Wkv    = (const float*)d_in[3];
  const float* Wo     = (const float*)d_in[4];
  const float* nullkv = (const float*)d_in[5];
  const float* qs     = (const float*)d_in[6];
  const float* ks     = (const float*)d_in[7];
  const float* g_in   = (const float*)d_in[8];
  const float* b_in   = (const float*)d_in[9];
  const float* g_ctx  = (const float*)d_in[10];
  const float* b_ctx  = (const float*)d_in[11];
  const float* g_out  = (const float*)d_in[12];
  const float* b_out  = (const float*)d_in[13];

  // Workspace plan (peak ~84 MB):
  //   wqT 0-2, wkvT 2-6, woT 6-8            (live: whole run)
  //   karr 8-11, varr 11-14                 (prep_kv -> attn)
  //   cn 14-16, kvb 16-20
  //   xn 20-52 (ln x -> gemm q)             qn 52-84 (gemm q -> attn, pre-normed)
  //   aout 20-52 (attn -> gemm o; overlays dead xn)
  //   out2h 52-84 f16 (gemm o -> ln out; overlays dead qn)
  char* ws = (char*)d_ws;
  const size_t MB = 1ull << 20;
  f16* wqT   = (f16*)(ws + 0);
  f16* wkvT  = (f16*)(ws + 2 * MB);
  f16* woT   = (f16*)(ws + 6 * MB);
  f16* karr  = (f16*)(ws + 8 * MB);
  f16* varr  = (f16*)(ws + 11 * MB);
  f16* cn    = (f16*)(ws + 14 * MB);
  f16* kvb   = (f16*)(ws + 16 * MB);
  f16* xn    = (f16*)(ws + 20 * MB);
  f16* qn    = (f16*)(ws + 52 * MB);
  f16* aout  = (f16*)(ws + 20 * MB);
  f16* out2h = (f16*)(ws + 52 * MB);

  transpose_all_kernel<<<4096, 256, 0, stream>>>(Wq, Wkv, Wo, wqT, wkvT, woT);

  ln_xc_kernel<<<16384 + 1024, 256, 0, stream>>>(x, ctx, g_in, b_in, g_ctx, b_ctx,
                                                 xn, cn);

  gemm_nt_kernel<true><<<(16384 / 128) * (1024 / 128), 256, 0, stream>>>(
      xn, wqT, qn, qs, 16384, 1024, 1024);
  gemm_nt_kernel<false><<<(1024 / 128) * (2048 / 128), 256, 0, stream>>>(
      cn, wkvT, kvb, nullptr, 1024, 2048, 1024);

  prep_kv_kernel<<<64, 256, 0, stream>>>(kvb, nullkv, ks, karr, varr);

  attn_kernel<<<2048, 256, 0, stream>>>(qn, karr, varr, qs, ks, aout);

  gemm_nt_kernel<false><<<(16384 / 128) * (1024 / 128), 256, 0, stream>>>(
      aout, woT, out2h, nullptr, 16384, 1024, 1024);

  ln_out_kernel<<<16384, 256, 0, stream>>>(out2h, g_out, b_out, (float*)d_out);
}

// Round 8
// 323.908 us; speedup vs baseline: 1.2478x; 1.0064x over previous
//
#include <hip/hip_runtime.h>
#include <cstdint>
#include <cstddef>

typedef _Float16 f16;
typedef _Float16 f16x4 __attribute__((ext_vector_type(4)));
typedef _Float16 f16x8 __attribute__((ext_vector_type(8)));
typedef float f32x4 __attribute__((ext_vector_type(4)));
typedef __fp16 h16x2 __attribute__((ext_vector_type(2)));

#define DIM 1024
#define B_ 4
#define N_ 4096
#define TKP 288           // padded key count (256 tokens + null + pad to 9*32)
#define SCALE_ 8.0f
#define LOG2E 1.4426950408889634f

// ---- async global->LDS, 16B per lane (CK-style addrspace casts) ----
__device__ __forceinline__ void gload_lds16(const void* g, void* l) {
  __builtin_amdgcn_global_load_lds(
      reinterpret_cast<const __attribute__((address_space(1))) uint32_t*>(
          reinterpret_cast<uintptr_t>(g)),
      reinterpret_cast<__attribute__((address_space(3))) uint32_t*>(
          reinterpret_cast<uintptr_t>(l)),
      16, 0, 0);
}

// ---- merged weight transposes: W fp32 [K][N] -> WT f16 [N][K] for Wq/Wkv/Wo ----
__global__ void transpose_all_kernel(const float* __restrict__ Wq,
                                     const float* __restrict__ Wkv,
                                     const float* __restrict__ Wo,
                                     f16* __restrict__ wqT, f16* __restrict__ wkvT,
                                     f16* __restrict__ woT) {
  int bid = blockIdx.x;            // 0..4095
  const float* W; f16* WT; int K = 1024, N; int tb;
  if (bid < 1024)      { W = Wq;  WT = wqT;  N = 1024; tb = bid; }
  else if (bid < 3072) { W = Wkv; WT = wkvT; N = 2048; tb = bid - 1024; }
  else                 { W = Wo;  WT = woT;  N = 1024; tb = bid - 3072; }
  __shared__ float tile[32][33];
  int nt = N >> 5;
  int tk = tb / nt, tn = tb % nt;
  int tx = threadIdx.x & 31, ty = threadIdx.x >> 5;  // 256 thr: ty 0..7
#pragma unroll
  for (int p = 0; p < 32; p += 8)
    tile[ty + p][tx] = W[(size_t)(tk * 32 + ty + p) * N + tn * 32 + tx];
  __syncthreads();
#pragma unroll
  for (int p = 0; p < 32; p += 8)
    WT[(size_t)(tn * 32 + ty + p) * K + tk * 32 + tx] = (f16)tile[tx][ty + p];
}

// ---- LayerNorm body over 1024 ----
__device__ __forceinline__ void ln_row_f16out(const float4 v, const float* g,
                                              const float* bb, int t, f16* outrow) {
  float s = v.x + v.y + v.z + v.w;
  float ss = v.x * v.x + v.y * v.y + v.z * v.z + v.w * v.w;
#pragma unroll
  for (int m = 1; m < 64; m <<= 1) { s += __shfl_xor(s, m); ss += __shfl_xor(ss, m); }
  __shared__ float red[8];
  int w = t >> 6;
  if ((t & 63) == 0) { red[w * 2] = s; red[w * 2 + 1] = ss; }
  __syncthreads();
  s = red[0] + red[2] + red[4] + red[6];
  ss = red[1] + red[3] + red[5] + red[7];
  float mean = s * (1.0f / DIM);
  float var = ss * (1.0f / DIM) - mean * mean;
  float rstd = rsqrtf(var + 1e-5f);
  float4 gv = ((const float4*)g)[t];
  float4 bv = ((const float4*)bb)[t];
  f16x4 h = {(f16)((v.x - mean) * rstd * gv.x + bv.x),
             (f16)((v.y - mean) * rstd * gv.y + bv.y),
             (f16)((v.z - mean) * rstd * gv.z + bv.z),
             (f16)((v.w - mean) * rstd * gv.w + bv.w)};
  *(f16x4*)(outrow + t * 4) = h;
}

// merged LN for x (16384 rows) and ctx (1024 rows), f32 in -> f16 out
__global__ void ln_xc_kernel(const float* __restrict__ x, const float* __restrict__ ctx,
                             const float* __restrict__ gx, const float* __restrict__ bx,
                             const float* __restrict__ gc, const float* __restrict__ bc,
                             f16* __restrict__ xn, f16* __restrict__ cn) {
  int row = blockIdx.x;
  int t = threadIdx.x;
  const float* in; const float* g; const float* bb; f16* out; int r;
  if (row < 16384) { in = x; g = gx; bb = bx; out = xn; r = row; }
  else             { in = ctx; g = gc; bb = bc; out = cn; r = row - 16384; }
  float4 v = ((const float4*)(in + (size_t)r * DIM))[t];
  ln_row_f16out(v, g, bb, t, out + (size_t)r * DIM);
}

// final LN: f16 in -> f32 out
__global__ void ln_out_kernel(const f16* __restrict__ in, const float* __restrict__ g,
                              const float* __restrict__ bb, float* __restrict__ out) {
  int row = blockIdx.x;
  int t = threadIdx.x;
  f16x4 h = ((const f16x4*)(in + (size_t)row * DIM))[t];
  float4 v = {(float)h[0], (float)h[1], (float)h[2], (float)h[3]};
  float s = v.x + v.y + v.z + v.w;
  float ss = v.x * v.x + v.y * v.y + v.z * v.z + v.w * v.w;
#pragma unroll
  for (int m = 1; m < 64; m <<= 1) { s += __shfl_xor(s, m); ss += __shfl_xor(ss, m); }
  __shared__ float red[8];
  int w = t >> 6;
  if ((t & 63) == 0) { red[w * 2] = s; red[w * 2 + 1] = ss; }
  __syncthreads();
  s = red[0] + red[2] + red[4] + red[6];
  ss = red[1] + red[3] + red[5] + red[7];
  float mean = s * (1.0f / DIM);
  float var = ss * (1.0f / DIM) - mean * mean;
  float rstd = rsqrtf(var + 1e-5f);
  float4 gv = ((const float4*)g)[t];
  float4 bv = ((const float4*)bb)[t];
  float4 o = {(v.x - mean) * rstd * gv.x + bv.x, (v.y - mean) * rstd * gv.y + bv.y,
              (v.z - mean) * rstd * gv.z + bv.z, (v.w - mean) * rstd * gv.w + bv.w};
  *(float4*)(out + (size_t)row * DIM + t * 4) = o;
}

// ---- NT GEMM: A f16 [M][K], Bt f16 [N][K], C = A*Bt^T (f16 out). 128x128 tile.
// NORMQ: fuse per-head (64-col group) row l2-norm * q_scale into the epilogue.
template <bool NORMQ>
__global__ __launch_bounds__(256, 2) void gemm_nt_kernel(
    const f16* __restrict__ A, const f16* __restrict__ Bt, f16* __restrict__ C,
    const float* __restrict__ qs, int M, int N, int K) {
  __shared__ f16 As[128 * 64];
  __shared__ f16 Bs[128 * 64];
  int nb = N >> 7;
  int cpx = gridDim.x >> 3;
  int wg = ((int)blockIdx.x & 7) * cpx + ((int)blockIdx.x >> 3);
  int bm = wg / nb, bn = wg % nb;
  int t = threadIdx.x;
  int lane = t & 63, w = t >> 6;
  int wm = w >> 1, wn = w & 1;       // 2x2 wave grid, each wave 64x64 output
  int r16 = lane & 15, g4 = lane >> 4;
  f32x4 acc[4][4] = {};
  for (int k0 = 0; k0 < K; k0 += 64) {
#pragma unroll
    for (int i = 0; i < 4; ++i) {
      int li = i * 256 + t;          // 0..1023 16B chunks
      int r = li >> 3, c = li & 7;
      int kc = ((c ^ (r & 7)) << 3); // element offset of swizzled chunk
      gload_lds16(A + (size_t)(bm * 128 + r) * K + k0 + kc, (char*)As + li * 16);
      gload_lds16(Bt + (size_t)(bn * 128 + r) * K + k0 + kc, (char*)Bs + li * 16);
    }
    __syncthreads();
#pragma unroll
    for (int ks = 0; ks < 2; ++ks) {
      f16x8 af[4], bf[4];
#pragma unroll
      for (int mi = 0; mi < 4; ++mi) {
        int r = wm * 64 + mi * 16 + r16;
        int cidx = ks * 4 + g4;
        af[mi] = *(const f16x8*)(As + r * 64 + ((cidx ^ (r & 7)) << 3));
      }
#pragma unroll
      for (int ni = 0; ni < 4; ++ni) {
        int r = wn * 64 + ni * 16 + r16;
        int cidx = ks * 4 + g4;
        bf[ni] = *(const f16x8*)(Bs + r * 64 + ((cidx ^ (r & 7)) << 3));
      }
#pragma unroll
      for (int mi = 0; mi < 4; ++mi)
#pragma unroll
        for (int ni = 0; ni < 4; ++ni)
          acc[mi][ni] = __builtin_amdgcn_mfma_f32_16x16x32_f16(af[mi], bf[ni],
                                                               acc[mi][ni], 0, 0, 0);
    }
    __syncthreads();
  }
  // epilogue: C/D layout col = lane&15, row = (lane>>4)*4 + reg
  int cr0 = bm * 128 + wm * 64;
  int cc = bn * 128 + wn * 64 + r16;
  float qsv[4];
  if constexpr (NORMQ) {
#pragma unroll
    for (int ni = 0; ni < 4; ++ni) qsv[ni] = qs[ni * 16 + r16];  // col % 64
  }
#pragma unroll
  for (int mi = 0; mi < 4; ++mi)
#pragma unroll
    for (int j = 0; j < 4; ++j) {
      float inv = 1.0f;
      if constexpr (NORMQ) {
        float ssq = 0.0f;
#pragma unroll
        for (int ni = 0; ni < 4; ++ni) ssq += acc[mi][ni][j] * acc[mi][ni][j];
        ssq += __shfl_xor(ssq, 1); ssq += __shfl_xor(ssq, 2);
        ssq += __shfl_xor(ssq, 4); ssq += __shfl_xor(ssq, 8);
        inv = 1.0f / fmaxf(sqrtf(ssq), 1e-12f);
      }
      int row = cr0 + mi * 16 + g4 * 4 + j;
#pragma unroll
      for (int ni = 0; ni < 4; ++ni) {
        float v = acc[mi][ni][j];
        if constexpr (NORMQ) v = v * inv * qsv[ni];
        C[(size_t)row * N + cc + ni * 16] = (f16)v;
      }
    }
}

// ---- build K [bh][288][64] (l2-norm * k_scale, null@256, zeros 257..287)
//      and V^T [bh][64][288] with keys PERMUTED within each 32-group:
//      key kk -> col 2*(kk&15) + (kk>>4), matching the packed-P k-slot order.
__global__ void prep_kv_kernel(const f16* __restrict__ kv, const float* __restrict__ nullkv,
                               const float* __restrict__ ks, f16* __restrict__ Karr,
                               f16* __restrict__ Varr) {
  int bh = blockIdx.x;           // 64 blocks
  int b = bh >> 4, h = bh & 15;
  int t = threadIdx.x;           // 256
  __shared__ f16 vt[256][65];
  const f16* krow = kv + (size_t)(b * 256 + t) * 2048 + h * 64;
  const f16* vrow = krow + 1024;
  f16x8 kd[8];
  float ss = 0.0f;
#pragma unroll
  for (int i = 0; i < 8; ++i) {
    kd[i] = *(const f16x8*)(krow + i * 8);
#pragma unroll
    for (int j = 0; j < 8; ++j) { float x = (float)kd[i][j]; ss += x * x; }
  }
  float inv = 1.0f / fmaxf(sqrtf(ss), 1e-12f);
  f16* kout = Karr + ((size_t)bh * TKP + t) * 64;
#pragma unroll
  for (int i = 0; i < 8; ++i) {
    f16x8 o;
#pragma unroll
    for (int j = 0; j < 8; ++j) o[j] = (f16)((float)kd[i][j] * inv * ks[i * 8 + j]);
    *(f16x8*)(kout + i * 8) = o;
  }
#pragma unroll
  for (int i = 0; i < 8; ++i) {
    f16x8 vv = *(const f16x8*)(vrow + i * 8);
#pragma unroll
    for (int j = 0; j < 8; ++j) vt[t][i * 8 + j] = vv[j];
  }
  if (t < 32) {   // K rows 256..287
    f16* kr = Karr + ((size_t)bh * TKP + 256 + t) * 64;
    if (t == 0) {
      float ssn = 0.0f;
      for (int d = 0; d < 64; ++d) ssn += nullkv[d] * nullkv[d];
      float invn = 1.0f / fmaxf(sqrtf(ssn), 1e-12f);
      for (int d = 0; d < 64; ++d) kr[d] = (f16)(nullkv[d] * invn * ks[d]);
    } else {
      for (int d = 0; d < 64; ++d) kr[d] = (f16)0.0f;
    }
  }
  __syncthreads();
  f16* vbase = Varr + (size_t)bh * 64 * TKP;
  int pcol = (t & ~31) | (((t & 15) << 1) | ((t >> 4) & 1));  // permuted key col
  for (int d = 0; d < 64; ++d) vbase[(size_t)d * TKP + pcol] = vt[t][d];
#pragma unroll
  for (int i = 0; i < 8; ++i) {      // V keys 256..287 (perm maps 256->256; rest zero)
    int idx = i * 256 + t;
    int d = idx >> 5, key = 256 + (idx & 31);
    vbase[(size_t)d * TKP + key] = (key == 256) ? (f16)nullkv[64 + d] : (f16)0.0f;
  }
}

// ---- flash attention, fixed-bound softmax + 3-buffer LDS staging (2 tiles
//      ahead, counted vmcnt) + LDS-transposed COALESCED O writes.
//      4 waves/block, 32 q-rows/wave, 9 x 32-key tiles.
__global__ __launch_bounds__(256, 4) void attn_kernel(
    const f16* __restrict__ Q, const f16* __restrict__ Karr,
    const f16* __restrict__ Varr, const float* __restrict__ qs,
    const float* __restrict__ ksc, f16* __restrict__ O) {
  // chunked XCD swizzle: 2048 blocks -> 256 contiguous per XCD (8 heads' K/V per L2)
  int wgid = ((int)blockIdx.x & 7) * 256 + ((int)blockIdx.x >> 3);
  int qb = wgid & 31, bh = wgid >> 5;
  int b = bh >> 4, h = bh & 15;
  int t = threadIdx.x, lane = t & 63, w = t >> 6;
  int r16 = lane & 15, g4 = lane >> 4;
  int row0 = b * N_ + qb * 128 + w * 32;
  int col0 = h * 64;
  const f16* Kp = Karr + (size_t)bh * TKP * 64;
  const f16* Vp = Varr + (size_t)bh * 64 * TKP;
  // manual LDS carve (single block so O-staging can safely overlay K/V bufs)
  __shared__ char smem[34816];
  f16* KsB = (f16*)smem;              // 3 x 4KB, [key][d] swizzled
  f16* VsB = (f16*)(smem + 12288);    // 3 x 4KB, [d][key(permuted)] swizzled
  f16* Pw = (f16*)(smem + 24576 + w * 2560);  // per-wave P [32][40]
  f16* Ob = (f16*)(smem + w * 4608);  // per-wave O staging [32][72], after loop
  // staging indices: thread t covers LDS bytes t*16; source chunk XOR-swizzled
  // so the ds_read side is conflict-free (rule #21).
  int krow_s = t >> 3;
  int kc_s = (t & 7) ^ (krow_s & 7);
  int vrow_s = t >> 2;
  int vc_s = (t & 3) ^ ((vrow_s >> 1) & 3);
  // stage tiles 0 and 1 (2 deep)
  gload_lds16(Kp + (size_t)krow_s * 64 + kc_s * 8, (char*)KsB + t * 16);
  gload_lds16(Vp + (size_t)vrow_s * TKP + 0 + vc_s * 8, (char*)VsB + t * 16);
  gload_lds16(Kp + (size_t)(32 + krow_s) * 64 + kc_s * 8,
              (char*)KsB + 4096 + t * 16);
  gload_lds16(Vp + (size_t)vrow_s * TKP + 32 + vc_s * 8,
              (char*)VsB + 4096 + t * 16);
  // score bound M = SCALE * max|qs| * max|ks|  (==8 for unit scales)
  float mq = fabsf(qs[lane]), mk = fabsf(ksc[lane]);
#pragma unroll
  for (int m = 1; m < 64; m <<= 1) {
    mq = fmaxf(mq, __shfl_xor(mq, m));
    mk = fmaxf(mk, __shfl_xor(mk, m));
  }
  const float c1 = SCALE_ * LOG2E;
  const float c2 = SCALE_ * mq * mk * LOG2E;
  // Q fragments (already l2-normed * q_scale by gemm_q epilogue)
  f16x8 qf[2][2];
#pragma unroll
  for (int mi = 0; mi < 2; ++mi)
#pragma unroll
    for (int kdh = 0; kdh < 2; ++kdh)
      qf[mi][kdh] = *(const f16x8*)(Q + (size_t)(row0 + mi * 16 + r16) * DIM +
                                    col0 + kdh * 32 + g4 * 8);
  f32x4 o[2][4] = {};
  float part[2][4] = {};   // per-lane partial softmax denominators
  const h16x2 ones2 = {(__fp16)1.0f, (__fp16)1.0f};
  // wait for stage(0) only (the 2 newest outstanding = stage(1) may fly)
  asm volatile("s_waitcnt vmcnt(2)" ::: "memory");
  __builtin_amdgcn_s_barrier();
  __builtin_amdgcn_sched_barrier(0);
#pragma unroll
  for (int kt = 0; kt < 9; ++kt) {
    const int cur = kt % 3;
    const int key0 = kt * 32;
    f16* Ks = KsB + cur * 2048;
    f16* Vs = VsB + cur * 2048;
    // issue staging two tiles ahead: buf[(kt+2)%3] == buf[(kt-1)%3], which all
    // waves finished reading before the barrier that ended tile kt-1.
    if (kt < 7) {
      const int nxt = key0 + 64;
      const int nbuf = (kt + 2) % 3;
      gload_lds16(Kp + (size_t)(nxt + krow_s) * 64 + kc_s * 8,
                  (char*)(KsB + nbuf * 2048) + t * 16);
      gload_lds16(Vp + (size_t)vrow_s * TKP + nxt + vc_s * 8,
                  (char*)(VsB + nbuf * 2048) + t * 16);
    }
    // K fragments from LDS (XOR-swizzled, 2-way max = free)
    f16x8 kf[2][2];
#pragma unroll
    for (int ni = 0; ni < 2; ++ni)
#pragma unroll
      for (int kdh = 0; kdh < 2; ++kdh) {
        int row = ni * 16 + r16;
        int cidx = kdh * 4 + g4;
        kf[ni][kdh] = *(const f16x8*)(Ks + row * 64 + ((cidx ^ (row & 7)) << 3));
      }
    f32x4 s[2][2] = {};
    __builtin_amdgcn_s_setprio(1);
#pragma unroll
    for (int kdh = 0; kdh < 2; ++kdh)
#pragma unroll
      for (int mi = 0; mi < 2; ++mi)
#pragma unroll
        for (int ni = 0; ni < 2; ++ni)
          s[mi][ni] = __builtin_amdgcn_mfma_f32_16x16x32_f16(qf[mi][kdh], kf[ni][kdh],
                                                             s[mi][ni], 0, 0, 0);
    __builtin_amdgcn_s_setprio(0);
    // softmax with mask folded into the exp bias (padded keys -> exp2 -> 0)
    float nb0 = (key0 + r16 <= 256) ? -c2 : -(c2 + 128.0f);
    float nb1 = (key0 + 16 + r16 <= 256) ? -c2 : -(c2 + 128.0f);
#pragma unroll
    for (int mi = 0; mi < 2; ++mi) {
#pragma unroll
      for (int j = 0; j < 4; ++j) {
        float p0 = __builtin_amdgcn_exp2f(s[mi][0][j] * c1 + nb0);
        float p1 = __builtin_amdgcn_exp2f(s[mi][1][j] * c1 + nb1);
        h16x2 pk = __builtin_amdgcn_cvt_pkrtz(p0, p1);
        part[mi][j] = __builtin_amdgcn_fdot2(pk, ones2, part[mi][j], false);
        int prow = mi * 16 + g4 * 4 + j;
        ((uint32_t*)(Pw + prow * 40))[r16] = __builtin_bit_cast(uint32_t, pk);
      }
    }
    // V fragments from LDS (swizzled slot, 2-way max = free)
    f16x8 vf[4];
#pragma unroll
    for (int nd = 0; nd < 4; ++nd) {
      int row = nd * 16 + r16;
      int slot = g4 ^ ((row >> 1) & 3);
      vf[nd] = *(const f16x8*)(Vs + row * 32 + (slot << 3));
    }
    __builtin_amdgcn_s_setprio(1);
#pragma unroll
    for (int mi = 0; mi < 2; ++mi) {
      f16x8 pa = *(const f16x8*)(Pw + (mi * 16 + r16) * 40 + g4 * 8);
#pragma unroll
      for (int nd = 0; nd < 4; ++nd)
        o[mi][nd] = __builtin_amdgcn_mfma_f32_16x16x32_f16(pa, vf[nd], o[mi][nd], 0, 0, 0);
    }
    __builtin_amdgcn_s_setprio(0);
    // end of tile: require stage(kt+1) complete; allow stage(kt+2)'s 2 loads
    // to stay in flight (counted vmcnt — never drain to 0 mid-loop).
    if (kt < 7) {
      asm volatile("s_waitcnt vmcnt(2)" ::: "memory");
      __builtin_amdgcn_s_barrier();
      __builtin_amdgcn_sched_barrier(0);
    } else if (kt == 7) {
      asm volatile("s_waitcnt vmcnt(0)" ::: "memory");
      __builtin_amdgcn_s_barrier();
      __builtin_amdgcn_sched_barrier(0);
    }
  }
  // deferred row-sum reduction (across the 16 r16 lanes)
#pragma unroll
  for (int mi = 0; mi < 2; ++mi)
#pragma unroll
    for (int j = 0; j < 4; ++j) {
      float v = part[mi][j];
      v += __shfl_xor(v, 1); v += __shfl_xor(v, 2);
      v += __shfl_xor(v, 4); v += __shfl_xor(v, 8);
      part[mi][j] = 1.0f / v;
    }
  // all waves done reading K/V LDS -> safe to overlay with O staging
  __builtin_amdgcn_s_barrier();
  // O transpose through per-wave LDS region [32 rows][72 f16 (64 used)]:
  // write fragment layout, read/store fully coalesced 128B rows.
#pragma unroll
  for (int mi = 0; mi < 2; ++mi)
#pragma unroll
    for (int j = 0; j < 4; ++j) {
      int row = mi * 16 + g4 * 4 + j;
#pragma unroll
      for (int nd = 0; nd < 4; ++nd)
        Ob[row * 72 + nd * 16 + r16] = (f16)(o[mi][nd][j] * part[mi][j]);
    }
  asm volatile("s_waitcnt lgkmcnt(0)" ::: "memory");
  __builtin_amdgcn_sched_barrier(0);
#pragma unroll
  for (int i = 0; i < 4; ++i) {
    int r = (lane >> 3) + i * 8;
    int c = (lane & 7) * 8;
    f16x8 v = *(const f16x8*)(Ob + r * 72 + c);
    *(f16x8*)(O + (size_t)(row0 + r) * DIM + col0 + c) = v;
  }
}

extern "C" void kernel_launch(void* const* d_in, const int* in_sizes, int n_in,
                              void* d_out, int out_size, void* d_ws, size_t ws_size,
                              hipStream_t stream) {
  const float* x      = (const float*)d_in[0];
  const float* ctx    = (const float*)d_in[1];
  const float* Wq     = (const float*)d_in[2];
  const float* Wkv    = (const float*)d_in[3];
  const float* Wo     = (const float*)d_in[4];
  const float* nullkv = (const float*)d_in[5];
  const float* qs     = (const float*)d_in[6];
  const float* ks     = (const float*)d_in[7];
  const float* g_in   = (const float*)d_in[8];
  const float* b_in   = (const float*)d_in[9];
  const float* g_ctx  = (const float*)d_in[10];
  const float* b_ctx  = (const float*)d_in[11];
  const float* g_out  = (const float*)d_in[12];
  const float* b_out  = (const float*)d_in[13];

  // Workspace plan (peak ~84 MB):
  //   wqT 0-2, wkvT 2-6, woT 6-8            (live: whole run)
  //   karr 8-11, varr 11-14                 (prep_kv -> attn)
  //   cn 14-16, kvb 16-20
  //   xn 20-52 (ln x -> gemm q)             qn 52-84 (gemm q -> attn, pre-normed)
  //   aout 20-52 (attn -> gemm o; overlays dead xn)
  //   out2h 52-84 f16 (gemm o -> ln out; overlays dead qn)
  char* ws = (char*)d_ws;
  const size_t MB = 1ull << 20;
  f16* wqT   = (f16*)(ws + 0);
  f16* wkvT  = (f16*)(ws + 2 * MB);
  f16* woT   = (f16*)(ws + 6 * MB);
  f16* karr  = (f16*)(ws + 8 * MB);
  f16* varr  = (f16*)(ws + 11 * MB);
  f16* cn    = (f16*)(ws + 14 * MB);
  f16* kvb   = (f16*)(ws + 16 * MB);
  f16* xn    = (f16*)(ws + 20 * MB);
  f16* qn    = (f16*)(ws + 52 * MB);
  f16* aout  = (f16*)(ws + 20 * MB);
  f16* out2h = (f16*)(ws + 52 * MB);

  transpose_all_kernel<<<4096, 256, 0, stream>>>(Wq, Wkv, Wo, wqT, wkvT, woT);

  ln_xc_kernel<<<16384 + 1024, 256, 0, stream>>>(x, ctx, g_in, b_in, g_ctx, b_ctx,
                                                 xn, cn);

  gemm_nt_kernel<true><<<(16384 / 128) * (1024 / 128), 256, 0, stream>>>(
      xn, wqT, qn, qs, 16384, 1024, 1024);
  gemm_nt_kernel<false><<<(1024 / 128) * (2048 / 128), 256, 0, stream>>>(
      cn, wkvT, kvb, nullptr, 1024, 2048, 1024);

  prep_kv_kernel<<<64, 256, 0, stream>>>(kvb, nullkv, ks, karr, varr);

  attn_kernel<<<2048, 256, 0, stream>>>(qn, karr, varr, qs, ks, aout);

  gemm_nt_kernel<false><<<(16384 / 128) * (1024 / 128), 256, 0, stream>>>(
      aout, woT, out2h, nullptr, 16384, 1024, 1024);

  ln_out_kernel<<<16384, 256, 0, stream>>>(out2h, g_out, b_out, (float*)d_out);
}